// Round 1
// baseline (1714.505 us; speedup 1.0000x reference)
//
#include <hip/hip_runtime.h>

#define S_LEN   2048
#define DM      1024
#define NH      16
#define DH      64
#define BATCH   2

// =====================================================================
// GEMM: C[M,N] = A[M,K] @ W[K,N] (+ bias[N] if bias)
// BM=BN=128, BK=32, 256 threads, 8x8 per thread.
// A staged transposed into LDS (Ast[k][m]) so inner loop does aligned
// float4 reads (conflict-free / 2-way); B staged direct (row-major).
// =====================================================================
__global__ __launch_bounds__(256) void gemm_bias(
    const float* __restrict__ A, const float* __restrict__ W,
    const float* __restrict__ bias, float* __restrict__ C,
    int M, int N, int K)
{
  __shared__ float Ast[32][132];
  __shared__ float Bst[32][132];
  const int t  = threadIdx.x;
  const int tx = t & 15, ty = t >> 4;
  const int n0 = blockIdx.x * 128;
  const int m0 = blockIdx.y * 128;

  float acc[8][8];
#pragma unroll
  for (int i = 0; i < 8; ++i)
#pragma unroll
    for (int j = 0; j < 8; ++j) acc[i][j] = 0.f;

  for (int k0 = 0; k0 < K; k0 += 32) {
    // A tile: 128 rows x 32 cols -> transposed
#pragma unroll
    for (int it = 0; it < 4; ++it) {
      int idx = t + it * 256;          // 0..1023
      int row = idx >> 3, dc = idx & 7;
      float4 v = *(const float4*)(A + (size_t)(m0 + row) * K + k0 + dc * 4);
      Ast[dc*4+0][row] = v.x;
      Ast[dc*4+1][row] = v.y;
      Ast[dc*4+2][row] = v.z;
      Ast[dc*4+3][row] = v.w;
    }
    // B tile: 32 rows x 128 cols -> direct
#pragma unroll
    for (int it = 0; it < 4; ++it) {
      int idx = t + it * 256;
      int kk = idx >> 5, nc = idx & 31;
      float4 v = *(const float4*)(W + (size_t)(k0 + kk) * N + n0 + nc * 4);
      *(float4*)&Bst[kk][nc*4] = v;
    }
    __syncthreads();
#pragma unroll
    for (int d = 0; d < 32; ++d) {
      float4 a0 = *(float4*)&Ast[d][ty*4];
      float4 a1 = *(float4*)&Ast[d][64 + ty*4];
      float4 b0 = *(float4*)&Bst[d][tx*4];
      float4 b1 = *(float4*)&Bst[d][64 + tx*4];
      float av[8] = {a0.x,a0.y,a0.z,a0.w,a1.x,a1.y,a1.z,a1.w};
      float bv[8] = {b0.x,b0.y,b0.z,b0.w,b1.x,b1.y,b1.z,b1.w};
#pragma unroll
      for (int i = 0; i < 8; ++i)
#pragma unroll
        for (int j = 0; j < 8; ++j)
          acc[i][j] = fmaf(av[i], bv[j], acc[i][j]);
    }
    __syncthreads();
  }

#pragma unroll
  for (int i = 0; i < 8; ++i) {
    int row = m0 + ((i < 4) ? (ty*4 + i) : (64 + ty*4 + (i - 4)));
#pragma unroll
    for (int jg = 0; jg < 2; ++jg) {
      int col = n0 + jg*64 + tx*4;
      float4 o;
      o.x = acc[i][jg*4+0]; o.y = acc[i][jg*4+1];
      o.z = acc[i][jg*4+2]; o.w = acc[i][jg*4+3];
      if (bias) {
        const float4 bb = *(const float4*)(bias + col);
        o.x += bb.x; o.y += bb.y; o.z += bb.z; o.w += bb.w;
      }
      *(float4*)(C + (size_t)row * N + col) = o;
    }
  }
}

// =====================================================================
// Score kernel: per (b,h) computes a 128x128 tile of
//   D[i,j] = sum_d (QP[b,i,h,d] + bias[h,d]) * KP[b,j,h,d]
// MODE==1 (pos): scatter through the rel-shift bijection, writing every
//   attn location exactly once (incl. the zero diagonal k=q+1).
// MODE==0 (content): coalesced read-modify-add into attn.
// =====================================================================
template <int MODE>
__global__ __launch_bounds__(256) void score_kernel(
    const float* __restrict__ QP, const float* __restrict__ KP,
    const float* __restrict__ bias_hd, float* __restrict__ attn)
{
  __shared__ float Ast[32][132];
  __shared__ float Bst[32][132];
  const int t  = threadIdx.x;
  const int tx = t & 15, ty = t >> 4;
  const int j0 = blockIdx.x * 128;
  const int i0 = blockIdx.y * 128;
  const int bh = blockIdx.z;
  const int b  = bh >> 4, h = bh & 15;

  const float* Ag = QP + (size_t)b * S_LEN * DM + h * DH;
  const float* Bg = KP + (size_t)b * S_LEN * DM + h * DH;
  const float* bias_h = bias_hd + h * DH;

  float acc[8][8];
#pragma unroll
  for (int i = 0; i < 8; ++i)
#pragma unroll
    for (int j = 0; j < 8; ++j) acc[i][j] = 0.f;

  for (int k0 = 0; k0 < DH; k0 += 32) {
#pragma unroll
    for (int it = 0; it < 4; ++it) {
      int idx = t + it * 256;
      int row = idx >> 3, dc = idx & 7;
      float4 v  = *(const float4*)(Ag + (size_t)(i0 + row) * DM + k0 + dc * 4);
      float4 ub = *(const float4*)(bias_h + k0 + dc * 4);
      Ast[dc*4+0][row] = v.x + ub.x;
      Ast[dc*4+1][row] = v.y + ub.y;
      Ast[dc*4+2][row] = v.z + ub.z;
      Ast[dc*4+3][row] = v.w + ub.w;
    }
#pragma unroll
    for (int it = 0; it < 4; ++it) {
      int idx = t + it * 256;
      int row = idx >> 3, dc = idx & 7;
      float4 v = *(const float4*)(Bg + (size_t)(j0 + row) * DM + k0 + dc * 4);
      Bst[dc*4+0][row] = v.x;
      Bst[dc*4+1][row] = v.y;
      Bst[dc*4+2][row] = v.z;
      Bst[dc*4+3][row] = v.w;
    }
    __syncthreads();
#pragma unroll
    for (int d = 0; d < 32; ++d) {
      float4 a0 = *(float4*)&Ast[d][ty*4];
      float4 a1 = *(float4*)&Ast[d][64 + ty*4];
      float4 b0 = *(float4*)&Bst[d][tx*4];
      float4 b1 = *(float4*)&Bst[d][64 + tx*4];
      float av[8] = {a0.x,a0.y,a0.z,a0.w,a1.x,a1.y,a1.z,a1.w};
      float bv[8] = {b0.x,b0.y,b0.z,b0.w,b1.x,b1.y,b1.z,b1.w};
#pragma unroll
      for (int i = 0; i < 8; ++i)
#pragma unroll
        for (int j = 0; j < 8; ++j)
          acc[i][j] = fmaf(av[i], bv[j], acc[i][j]);
    }
    __syncthreads();
  }

  float* attn_bh = attn + (size_t)bh * S_LEN * S_LEN;

  if (MODE == 0) {
    // content: add into attn (already fully written by pos pass)
#pragma unroll
    for (int i = 0; i < 8; ++i) {
      int gi = i0 + ((i < 4) ? (ty*4 + i) : (64 + ty*4 + (i - 4)));
#pragma unroll
      for (int jg = 0; jg < 2; ++jg) {
        int gj = j0 + jg*64 + tx*4;
        float4* p = (float4*)(attn_bh + (size_t)gi * S_LEN + gj);
        float4 v = *p;
        v.x += acc[i][jg*4+0]; v.y += acc[i][jg*4+1];
        v.z += acc[i][jg*4+2]; v.w += acc[i][jg*4+3];
        *p = v;
      }
    }
  } else {
    // pos: rel-shift scatter. PS[gi,gj] maps to exactly one target;
    // unused PS[0, gj<S-1] slots write the zero diagonal rel[gj, gj+1].
#pragma unroll
    for (int i = 0; i < 8; ++i) {
      int gi = i0 + ((i < 4) ? (ty*4 + i) : (64 + ty*4 + (i - 4)));
#pragma unroll
      for (int j = 0; j < 8; ++j) {
        int gj = j0 + ((j < 4) ? (tx*4 + j) : (64 + tx*4 + (j - 4)));
        float val = acc[i][j];
        int tr, tc; float wv;
        if (gi == 0) {
          if (gj == S_LEN - 1) { tr = 0; tc = 0; wv = val; }
          else                 { tr = gj; tc = gj + 1; wv = 0.f; }
        } else if (gj >= S_LEN - 1 - gi) {
          tr = gi;     tc = gi + gj - (S_LEN - 1); wv = val;
        } else {
          tr = gi - 1; tc = gi + gj + 1;           wv = val;
        }
        attn_bh[(size_t)tr * S_LEN + tc] = wv;
      }
    }
  }
}

// =====================================================================
// Row softmax over attn rows (length S_LEN), with 1/sqrt(DM)=1/32 scale.
// One 256-thread block per row; 8 elements per thread kept in registers.
// =====================================================================
__global__ __launch_bounds__(256) void softmax_kernel(float* __restrict__ attn)
{
  const size_t row = blockIdx.x;
  float* p = attn + row * (size_t)S_LEN;
  const int t = threadIdx.x;

  float4 v0 = ((const float4*)p)[t];
  float4 v1 = ((const float4*)p)[t + 256];
  const float s = 0.03125f;  // 1/sqrt(1024)
  float x[8] = {v0.x*s, v0.y*s, v0.z*s, v0.w*s, v1.x*s, v1.y*s, v1.z*s, v1.w*s};

  float m = x[0];
#pragma unroll
  for (int j = 1; j < 8; ++j) m = fmaxf(m, x[j]);
#pragma unroll
  for (int off = 1; off < 64; off <<= 1) m = fmaxf(m, __shfl_xor(m, off));

  __shared__ float sm[4];
  __shared__ float ss[4];
  const int wid = t >> 6, lane = t & 63;
  if (lane == 0) sm[wid] = m;
  __syncthreads();
  m = fmaxf(fmaxf(sm[0], sm[1]), fmaxf(sm[2], sm[3]));

  float e[8]; float sum = 0.f;
#pragma unroll
  for (int j = 0; j < 8; ++j) { e[j] = __expf(x[j] - m); sum += e[j]; }
#pragma unroll
  for (int off = 1; off < 64; off <<= 1) sum += __shfl_xor(sum, off);
  if (lane == 0) ss[wid] = sum;
  __syncthreads();
  sum = (ss[0] + ss[1]) + (ss[2] + ss[3]);
  const float r = 1.f / sum;

  float4 o0, o1;
  o0.x = e[0]*r; o0.y = e[1]*r; o0.z = e[2]*r; o0.w = e[3]*r;
  o1.x = e[4]*r; o1.y = e[5]*r; o1.z = e[6]*r; o1.w = e[7]*r;
  ((float4*)p)[t]       = o0;
  ((float4*)p)[t + 256] = o1;
}

// =====================================================================
// context[b,q,h,:] = sum_k attn[b,h,q,k] * v[b,k,h,:]
// Tile: 128 q-rows x 64 dh, K-loop over S in steps of 32.
// =====================================================================
__global__ __launch_bounds__(256) void av_kernel(
    const float* __restrict__ attn, const float* __restrict__ V,
    float* __restrict__ ctx)
{
  __shared__ float At[32][132];
  __shared__ float Bv[32][72];
  const int t  = threadIdx.x;
  const int tx = t & 15, ty = t >> 4;
  const int q0 = blockIdx.x * 128;
  const int bh = blockIdx.y;
  const int b  = bh >> 4, h = bh & 15;

  const float* Ab = attn + (size_t)bh * S_LEN * S_LEN;
  const float* Vg = V + (size_t)b * S_LEN * DM + h * DH;

  float acc[8][4];
#pragma unroll
  for (int i = 0; i < 8; ++i)
#pragma unroll
    for (int j = 0; j < 4; ++j) acc[i][j] = 0.f;

  for (int k0 = 0; k0 < S_LEN; k0 += 32) {
#pragma unroll
    for (int it = 0; it < 4; ++it) {
      int idx = t + it * 256;
      int row = idx >> 3, dc = idx & 7;
      float4 v = *(const float4*)(Ab + (size_t)(q0 + row) * S_LEN + k0 + dc * 4);
      At[dc*4+0][row] = v.x;
      At[dc*4+1][row] = v.y;
      At[dc*4+2][row] = v.z;
      At[dc*4+3][row] = v.w;
    }
#pragma unroll
    for (int it = 0; it < 2; ++it) {
      int idx = t + it * 256;
      int kk = idx >> 4, dc = idx & 15;
      float4 v = *(const float4*)(Vg + (size_t)(k0 + kk) * DM + dc * 4);
      *(float4*)&Bv[kk][dc*4] = v;
    }
    __syncthreads();
#pragma unroll
    for (int d = 0; d < 32; ++d) {
      float4 a0 = *(float4*)&At[d][ty*4];
      float4 a1 = *(float4*)&At[d][64 + ty*4];
      float4 b0 = *(float4*)&Bv[d][tx*4];
      float av[8] = {a0.x,a0.y,a0.z,a0.w,a1.x,a1.y,a1.z,a1.w};
      float bv[4] = {b0.x,b0.y,b0.z,b0.w};
#pragma unroll
      for (int i = 0; i < 8; ++i)
#pragma unroll
        for (int j = 0; j < 4; ++j)
          acc[i][j] = fmaf(av[i], bv[j], acc[i][j]);
    }
    __syncthreads();
  }

#pragma unroll
  for (int i = 0; i < 8; ++i) {
    int row = q0 + ((i < 4) ? (ty*4 + i) : (64 + ty*4 + (i - 4)));
    float4 o;
    o.x = acc[i][0]; o.y = acc[i][1]; o.z = acc[i][2]; o.w = acc[i][3];
    *(float4*)(ctx + (size_t)(b * S_LEN + row) * DM + h * DH + tx * 4) = o;
  }
}

// =====================================================================
extern "C" void kernel_launch(void* const* d_in, const int* in_sizes, int n_in,
                              void* d_out, int out_size, void* d_ws, size_t ws_size,
                              hipStream_t stream)
{
  (void)in_sizes; (void)n_in; (void)out_size; (void)ws_size;

  const float* query  = (const float*)d_in[0];
  const float* key    = (const float*)d_in[1];
  const float* value  = (const float*)d_in[2];
  const float* pos    = (const float*)d_in[3];
  const float* Wq     = (const float*)d_in[4];
  const float* bq     = (const float*)d_in[5];
  const float* Wk     = (const float*)d_in[6];
  const float* bk     = (const float*)d_in[7];
  const float* Wv     = (const float*)d_in[8];
  const float* bv     = (const float*)d_in[9];
  const float* Wpos   = (const float*)d_in[10];
  const float* u_bias = (const float*)d_in[11];
  const float* v_bias = (const float*)d_in[12];
  const float* Wout   = (const float*)d_in[13];
  const float* bout   = (const float*)d_in[14];

  float* out  = (float*)d_out;
  float* attn = out + (size_t)BATCH * S_LEN * DM;

  const size_t proj_sz = (size_t)BATCH * S_LEN * DM;
  float* ws = (float*)d_ws;
  float* qp = ws;
  float* kp = ws + proj_sz;
  float* vp = ws + 2 * proj_sz;
  float* pp = ws + 3 * proj_sz;
  float* ctx = qp;  // qp is dead after the two score kernels

  const int M = BATCH * S_LEN;
  dim3 blk(256);
  dim3 g_proj(DM / 128, M / 128);

  gemm_bias<<<g_proj, blk, 0, stream>>>(query, Wq, bq, qp, M, DM, DM);
  gemm_bias<<<g_proj, blk, 0, stream>>>(key,   Wk, bk, kp, M, DM, DM);
  gemm_bias<<<g_proj, blk, 0, stream>>>(value, Wv, bv, vp, M, DM, DM);
  gemm_bias<<<g_proj, blk, 0, stream>>>(pos,   Wpos, nullptr, pp, M, DM, DM);

  dim3 g_sc(S_LEN / 128, S_LEN / 128, BATCH * NH);
  // pos pass first: writes every attn element exactly once (scatter + zero diag)
  score_kernel<1><<<g_sc, blk, 0, stream>>>(qp, pp, v_bias, attn);
  // content pass: coalesced add
  score_kernel<0><<<g_sc, blk, 0, stream>>>(qp, kp, u_bias, attn);

  softmax_kernel<<<dim3(BATCH * NH * S_LEN), blk, 0, stream>>>(attn);

  av_kernel<<<dim3(S_LEN / 128, BATCH * NH), blk, 0, stream>>>(attn, vp, ctx);

  gemm_bias<<<g_proj, blk, 0, stream>>>(ctx, Wout, bout, out, M, DM, DM);
}

// Round 2
// 690.925 us; speedup vs baseline: 2.4815x; 2.4815x over previous
//
#include <hip/hip_runtime.h>

#define S_LEN 2048
#define DM    1024
#define NH    16
#define DH    64
#define BATCH 2
#define S2    ((size_t)S_LEN * S_LEN)

typedef _Float16 half_t;
typedef _Float16 f16x8 __attribute__((ext_vector_type(8)));
typedef float    f32x4 __attribute__((ext_vector_type(4)));

// =====================================================================
// LDS staging: 128 rows x 64 k (f16), 8-half chunks, XOR swizzle
// chunk' = c ^ (row&7)  -> conflict-free ds_read_b128 fragments (G4/T2)
// =====================================================================
__device__ __forceinline__ void stage_tile_f32(half_t* dst, const float* src, int row_stride) {
  const int t = threadIdx.x;
#pragma unroll
  for (int it = 0; it < 4; ++it) {
    int idx = t + it * 256; int r = idx >> 3, c = idx & 7;
    const float4* g = (const float4*)(src + (size_t)r * row_stride + c * 8);
    float4 v0 = g[0], v1 = g[1];
    f16x8 h;
    h[0] = (half_t)v0.x; h[1] = (half_t)v0.y; h[2] = (half_t)v0.z; h[3] = (half_t)v0.w;
    h[4] = (half_t)v1.x; h[5] = (half_t)v1.y; h[6] = (half_t)v1.z; h[7] = (half_t)v1.w;
    *(f16x8*)&dst[(size_t)(r * 8 + (c ^ (r & 7))) * 8] = h;
  }
}

__device__ __forceinline__ void stage_tile_f16(half_t* dst, const half_t* src, int row_stride) {
  const int t = threadIdx.x;
#pragma unroll
  for (int it = 0; it < 4; ++it) {
    int idx = t + it * 256; int r = idx >> 3, c = idx & 7;
    uint4 v = *(const uint4*)(src + (size_t)r * row_stride + c * 8);
    *(uint4*)&dst[(size_t)(r * 8 + (c ^ (r & 7))) * 8] = v;
  }
}

// per-wave 32 rows x 128 cols over K=64 (2 mfma k-steps)
__device__ __forceinline__ void mfma_block(const half_t* At, const half_t* Bt,
                                           int w, int lane, f32x4 acc[2][8]) {
  const int grp = lane >> 4, li = lane & 15;
#pragma unroll
  for (int ks = 0; ks < 2; ++ks) {
    const int chunk = ks * 4 + grp;
    f16x8 a[2], b[8];
#pragma unroll
    for (int fr = 0; fr < 2; ++fr) {
      int r = w * 32 + fr * 16 + li;
      a[fr] = *(const f16x8*)&At[(size_t)(r * 8 + (chunk ^ (r & 7))) * 8];
    }
#pragma unroll
    for (int fc = 0; fc < 8; ++fc) {
      int r = fc * 16 + li;
      b[fc] = *(const f16x8*)&Bt[(size_t)(r * 8 + (chunk ^ (r & 7))) * 8];
    }
#pragma unroll
    for (int fr = 0; fr < 2; ++fr)
#pragma unroll
      for (int fc = 0; fc < 8; ++fc)
        acc[fr][fc] = __builtin_amdgcn_mfma_f32_16x16x32_f16(a[fr], b[fc], acc[fr][fc], 0, 0, 0);
  }
}

template<typename ST>
__device__ __forceinline__ void load8s(const ST* p, float* o) {
  if constexpr (sizeof(ST) == 2) {
    f16x8 v = *(const f16x8*)p;
#pragma unroll
    for (int e = 0; e < 8; ++e) o[e] = (float)v[e];
  } else {
    const float4* q = (const float4*)p;
    float4 a = q[0], b = q[1];
    o[0]=a.x; o[1]=a.y; o[2]=a.z; o[3]=a.w; o[4]=b.x; o[5]=b.y; o[6]=b.z; o[7]=b.w;
  }
}

// =====================================================================
// Weight convert + transpose: W[k][n] f32 -> Wt[n][k] f16  (5 matrices)
// =====================================================================
struct WArgs { const float* src[5]; half_t* dst[5]; };

__global__ __launch_bounds__(256) void wconv(WArgs wa) {
  __shared__ float T[64][65];
  const float* W = wa.src[blockIdx.z];
  half_t* D = wa.dst[blockIdx.z];
  const int k0 = blockIdx.x * 64, n0 = blockIdx.y * 64;
  const int t = threadIdx.x;
#pragma unroll
  for (int it = 0; it < 4; ++it) {
    int idx = t + it * 256; int r = idx >> 4, c4 = (idx & 15) * 4;
    float4 v = *(const float4*)(W + (size_t)(k0 + r) * DM + n0 + c4);
    T[r][c4] = v.x; T[r][c4 + 1] = v.y; T[r][c4 + 2] = v.z; T[r][c4 + 3] = v.w;
  }
  __syncthreads();
#pragma unroll
  for (int it = 0; it < 2; ++it) {
    int idx = t + it * 256; int n = idx >> 3, kc = (idx & 7) * 8;
    f16x8 o;
#pragma unroll
    for (int e = 0; e < 8; ++e) o[e] = (half_t)T[kc + e][n];
    *(f16x8*)&D[(size_t)(n0 + n) * DM + k0 + kc] = o;
  }
}

// =====================================================================
// GEMM: C[M,1024] = A[M,1024] @ Wt[n][k]^T ; z-indexed operand sets.
// Epilogue: oa = acc + ba + bu ; ob = acc + ba + bv (dual, for q) ; or f32 out.
// =====================================================================
struct GArgs {
  const void*  A[4];  const half_t* Bt[4];
  const float* ba[4]; const float* bu[4]; const float* bv[4];
  half_t* oa[4]; half_t* ob[4]; float* of[4];
};

template<typename AT, bool F32OUT>
__global__ __launch_bounds__(256) void gemm_k(GArgs g, int K) {
  __shared__ __align__(16) half_t At[128 * 64];
  __shared__ __align__(16) half_t Bt[128 * 64];
  const int z = blockIdx.z;
  const AT* A = (const AT*)g.A[z];
  const half_t* B = g.Bt[z];
  const int n0 = blockIdx.x * 128, m0 = blockIdx.y * 128;
  const int t = threadIdx.x, w = t >> 6, lane = t & 63;
  const f32x4 zf = {0.f, 0.f, 0.f, 0.f};
  f32x4 acc[2][8];
#pragma unroll
  for (int i = 0; i < 2; ++i)
#pragma unroll
    for (int j = 0; j < 8; ++j) acc[i][j] = zf;

  for (int k0 = 0; k0 < K; k0 += 64) {
    if constexpr (sizeof(AT) == 4) stage_tile_f32(At, (const float*)A + (size_t)m0 * K + k0, K);
    else                           stage_tile_f16(At, (const half_t*)A + (size_t)m0 * K + k0, K);
    stage_tile_f16(Bt, B + (size_t)n0 * K + k0, K);
    __syncthreads();
    mfma_block(At, Bt, w, lane, acc);
    __syncthreads();
  }
  const int grp = lane >> 4, li = lane & 15;
#pragma unroll
  for (int fr = 0; fr < 2; ++fr)
#pragma unroll
    for (int fc = 0; fc < 8; ++fc)
#pragma unroll
      for (int r = 0; r < 4; ++r) {
        int row = m0 + w * 32 + fr * 16 + grp * 4 + r;
        int col = n0 + fc * 16 + li;
        float v = acc[fr][fc][r];
        if (g.ba[z]) v += g.ba[z][col];
        if constexpr (F32OUT) {
          g.of[z][(size_t)row * DM + col] = v;
        } else {
          float v1 = v + (g.bu[z] ? g.bu[z][col] : 0.f);
          g.oa[z][(size_t)row * DM + col] = (half_t)v1;
          if (g.ob[z]) g.ob[z][(size_t)row * DM + col] = (half_t)(v + g.bv[z][col]);
        }
      }
}

// =====================================================================
// V transpose per head: vp[b*S+s][h*64+d] -> vT[bh][d][s]  (f16)
// =====================================================================
__global__ __launch_bounds__(256) void vtrans(const half_t* vp, half_t* vT) {
  __shared__ half_t T[64][72];
  const int s0 = blockIdx.x * 64, h = blockIdx.y, b = blockIdx.z;
  const int t = threadIdx.x;
#pragma unroll
  for (int it = 0; it < 2; ++it) {
    int idx = t + it * 256; int s = idx >> 3, c = idx & 7;
    uint4 v = *(const uint4*)(vp + ((size_t)(b * S_LEN + s0 + s)) * DM + h * DH + c * 8);
    *(uint4*)&T[s][c * 8] = v;
  }
  __syncthreads();
  half_t* dst = vT + ((size_t)(b * NH + h)) * DH * S_LEN;
#pragma unroll
  for (int it = 0; it < 2; ++it) {
    int idx = t + it * 256; int d = idx >> 3, sc = (idx & 7) * 8;
    f16x8 o;
#pragma unroll
    for (int e = 0; e < 8; ++e) o[e] = T[sc + e][d];
    *(f16x8*)&dst[(size_t)d * S_LEN + s0 + sc] = o;
  }
}

// =====================================================================
// Pass 1: pos scores B[i,j]=(q+v_bias)_i · p_j, scattered via rel-shift
// bijection (incl. zero diagonal) -> sc (raw, unscaled).
// =====================================================================
template<typename ST>
__global__ __launch_bounds__(256) void score_pos(const half_t* qv_, const half_t* pp_, ST* sc) {
  __shared__ __align__(16) half_t At[128 * 64];
  __shared__ __align__(16) half_t Bt[128 * 64];
  const int bh = blockIdx.z, b = bh >> 4, h = bh & 15;
  const int j0 = blockIdx.x * 128, i0 = blockIdx.y * 128;
  const int t = threadIdx.x, w = t >> 6, lane = t & 63;
  stage_tile_f16(At, qv_ + ((size_t)(b * S_LEN + i0)) * DM + h * DH, DM);
  stage_tile_f16(Bt, pp_ + ((size_t)(b * S_LEN + j0)) * DM + h * DH, DM);
  __syncthreads();
  const f32x4 zf = {0.f, 0.f, 0.f, 0.f};
  f32x4 acc[2][8];
#pragma unroll
  for (int i = 0; i < 2; ++i)
#pragma unroll
    for (int j = 0; j < 8; ++j) acc[i][j] = zf;
  mfma_block(At, Bt, w, lane, acc);

  ST* sb = sc + (size_t)bh * S2;
  const int grp = lane >> 4, li = lane & 15;
#pragma unroll
  for (int fr = 0; fr < 2; ++fr)
#pragma unroll
    for (int fc = 0; fc < 8; ++fc)
#pragma unroll
      for (int r = 0; r < 4; ++r) {
        int gi = i0 + w * 32 + fr * 16 + grp * 4 + r;
        int gj = j0 + fc * 16 + li;
        float val = acc[fr][fc][r];
        int tr, tc; float wv;
        if (gi == 0) {
          if (gj == S_LEN - 1) { tr = 0; tc = 0; wv = val; }
          else                 { tr = gj; tc = gj + 1; wv = 0.f; }
        } else if (gj >= S_LEN - 1 - gi) {
          tr = gi;     tc = gi + gj - (S_LEN - 1); wv = val;
        } else {
          tr = gi - 1; tc = gi + gj + 1;           wv = val;
        }
        sb[(size_t)tr * S_LEN + tc] = (ST)wv;
      }
}

// =====================================================================
// Pass 2: content scores (q+u_bias)_i · k_j, RMW-add onto sc, apply /32,
// and emit per-(row, 128-col-tile) softmax partials (max, sumexp).
// =====================================================================
template<typename ST>
__global__ __launch_bounds__(256) void score_content(const half_t* qu_, const half_t* kp_,
                                                     ST* sc, float2* part) {
  __shared__ __align__(16) half_t At[128 * 64];
  __shared__ __align__(16) half_t Bt[128 * 64];
  const int bh = blockIdx.z, b = bh >> 4, h = bh & 15;
  const int k0 = blockIdx.x * 128, i0 = blockIdx.y * 128;
  const int kt = blockIdx.x;
  const int t = threadIdx.x, w = t >> 6, lane = t & 63;
  stage_tile_f16(At, qu_ + ((size_t)(b * S_LEN + i0)) * DM + h * DH, DM);
  stage_tile_f16(Bt, kp_ + ((size_t)(b * S_LEN + k0)) * DM + h * DH, DM);
  __syncthreads();
  const f32x4 zf = {0.f, 0.f, 0.f, 0.f};
  f32x4 acc[2][8];
#pragma unroll
  for (int i = 0; i < 2; ++i)
#pragma unroll
    for (int j = 0; j < 8; ++j) acc[i][j] = zf;
  mfma_block(At, Bt, w, lane, acc);

  ST* sb = sc + (size_t)bh * S2;
  const int grp = lane >> 4, li = lane & 15;
#pragma unroll
  for (int fr = 0; fr < 2; ++fr)
#pragma unroll
    for (int r = 0; r < 4; ++r) {
      int row = i0 + w * 32 + fr * 16 + grp * 4 + r;
      float s[8];
#pragma unroll
      for (int fc = 0; fc < 8; ++fc) {
        int col = k0 + fc * 16 + li;
        size_t off = (size_t)row * S_LEN + col;
        float v = (acc[fr][fc][r] + (float)sb[off]) * 0.03125f;
        sb[off] = (ST)v;
        s[fc] = v;
      }
      float m = s[0];
#pragma unroll
      for (int fc = 1; fc < 8; ++fc) m = fmaxf(m, s[fc]);
#pragma unroll
      for (int d = 1; d < 16; d <<= 1) m = fmaxf(m, __shfl_xor(m, d));
      float l = 0.f;
#pragma unroll
      for (int fc = 0; fc < 8; ++fc) l += __expf(s[fc] - m);
#pragma unroll
      for (int d = 1; d < 16; d <<= 1) l += __shfl_xor(l, d);
      if (li == 0) part[((size_t)bh * S_LEN + row) * 16 + kt] = make_float2(m, l);
    }
}

// =====================================================================
// Pass 3: combine partials -> (M, 1/L); stream score tiles, write final
// f32 attn ONCE, and MFMA p@V -> ctx (f16).  In-place safe for ST=float.
// =====================================================================
template<typename ST>
__global__ __launch_bounds__(256) void av_attn(const ST* sc, const half_t* vT, const float2* part,
                                               float* attn, half_t* ctx) {
  __shared__ __align__(16) half_t Vt[64 * 128];
  __shared__ float Ms[128], Ls[128];
  const int bh = blockIdx.y, b = bh >> 4, h = bh & 15;
  const int q0 = blockIdx.x * 128;
  const int t = threadIdx.x;
  if (t < 128) {
    const float2* pp = part + ((size_t)bh * S_LEN + q0 + t) * 16;
    float M = -3.0e38f;
#pragma unroll
    for (int k = 0; k < 16; ++k) M = fmaxf(M, pp[k].x);
    float L = 0.f;
#pragma unroll
    for (int k = 0; k < 16; ++k) { float2 v = pp[k]; L += v.y * __expf(v.x - M); }
    Ms[t] = M; Ls[t] = 1.f / L;
  }
  const ST* sb = sc + (size_t)bh * S2;
  float* ab = attn + (size_t)bh * S2;
  const half_t* vb = vT + (size_t)bh * (DH * S_LEN);
  const int w = t >> 6, lane = t & 63, grp = lane >> 4, li = lane & 15;
  const f32x4 zf = {0.f, 0.f, 0.f, 0.f};
  f32x4 acc[2][4];
#pragma unroll
  for (int i = 0; i < 2; ++i)
#pragma unroll
    for (int j = 0; j < 4; ++j) acc[i][j] = zf;

  for (int kt = 0; kt < 16; ++kt) {
    __syncthreads();
#pragma unroll
    for (int it = 0; it < 4; ++it) {
      int idx = t + it * 256; int d = idx >> 4, c = idx & 15;
      uint4 v = *(const uint4*)(vb + (size_t)d * S_LEN + kt * 128 + c * 8);
      *(uint4*)&Vt[(size_t)(d * 16 + (c ^ (d & 15))) * 8] = v;
    }
    __syncthreads();
#pragma unroll
    for (int ks = 0; ks < 4; ++ks) {
      f16x8 pa[2];
#pragma unroll
      for (int fr = 0; fr < 2; ++fr) {
        int r128 = w * 32 + fr * 16 + li;
        int row = q0 + r128;
        int col = kt * 128 + ks * 32 + grp * 8;
        float sv[8];
        load8s(&sb[(size_t)row * S_LEN + col], sv);
        float M = Ms[r128], rL = Ls[r128];
#pragma unroll
        for (int e = 0; e < 8; ++e) sv[e] = __expf(sv[e] - M) * rL;
        float4* dst = (float4*)&ab[(size_t)row * S_LEN + col];
        float4 w0 = {sv[0], sv[1], sv[2], sv[3]};
        float4 w1 = {sv[4], sv[5], sv[6], sv[7]};
        dst[0] = w0; dst[1] = w1;
        f16x8 ph;
#pragma unroll
        for (int e = 0; e < 8; ++e) ph[e] = (half_t)sv[e];
        pa[fr] = ph;
      }
      f16x8 bf[4];
#pragma unroll
      for (int fc = 0; fc < 4; ++fc) {
        int d = fc * 16 + li; int chunk = ks * 4 + grp;
        bf[fc] = *(const f16x8*)&Vt[(size_t)(d * 16 + (chunk ^ (d & 15))) * 8];
      }
#pragma unroll
      for (int fr = 0; fr < 2; ++fr)
#pragma unroll
        for (int fc = 0; fc < 4; ++fc)
          acc[fr][fc] = __builtin_amdgcn_mfma_f32_16x16x32_f16(pa[fr], bf[fc], acc[fr][fc], 0, 0, 0);
    }
  }
#pragma unroll
  for (int fr = 0; fr < 2; ++fr)
#pragma unroll
    for (int fc = 0; fc < 4; ++fc)
#pragma unroll
      for (int r = 0; r < 4; ++r) {
        int q = q0 + w * 32 + fr * 16 + grp * 4 + r;
        int d = fc * 16 + li;
        ctx[((size_t)(b * S_LEN + q)) * DM + h * DH + d] = (half_t)acc[fr][fc][r];
      }
}

// =====================================================================
extern "C" void kernel_launch(void* const* d_in, const int* in_sizes, int n_in,
                              void* d_out, int out_size, void* d_ws, size_t ws_size,
                              hipStream_t stream) {
  (void)in_sizes; (void)n_in; (void)out_size;

  const float* query  = (const float*)d_in[0];
  const float* key    = (const float*)d_in[1];
  const float* value  = (const float*)d_in[2];
  const float* pos    = (const float*)d_in[3];
  const float* Wq     = (const float*)d_in[4];
  const float* bq     = (const float*)d_in[5];
  const float* Wk     = (const float*)d_in[6];
  const float* bk     = (const float*)d_in[7];
  const float* Wv     = (const float*)d_in[8];
  const float* bv     = (const float*)d_in[9];
  const float* Wpos   = (const float*)d_in[10];
  const float* u_bias = (const float*)d_in[11];  // [16,64] == flat [1024]
  const float* v_bias = (const float*)d_in[12];
  const float* Wout   = (const float*)d_in[13];
  const float* bout   = (const float*)d_in[14];

  float* out  = (float*)d_out;
  float* attn = out + (size_t)BATCH * S_LEN * DM;

  char* ws = (char*)d_ws;
  half_t* Wt  = (half_t*)(ws);                  // 5 x 1024x1024 f16 = 10,485,760 B
  half_t* qu  = (half_t*)(ws + 10485760);       // each proj: 8,388,608 B
  half_t* qv  = (half_t*)(ws + 18874368);
  half_t* kp  = (half_t*)(ws + 27262976);
  half_t* pp  = (half_t*)(ws + 35651584);
  half_t* vp  = (half_t*)(ws + 44040192);
  half_t* vT  = (half_t*)(ws + 52428800);
  float2* part = (float2*)(ws + 35651584);      // alias pp (dead after pass 1)
  half_t* ctx  = (half_t*)(ws + 44040192);      // alias vp (dead after vtrans)
  half_t* scH  = (half_t*)(ws + 60817408);      // 268,435,456 B if it fits
  const bool fast = ws_size >= (size_t)60817408 + (size_t)BATCH * NH * S2 * 2;

  dim3 blk(256);

  // 1. weights -> f16, transposed [n][k]
  WArgs wa;
  wa.src[0] = Wq; wa.src[1] = Wk; wa.src[2] = Wv; wa.src[3] = Wpos; wa.src[4] = Wout;
  for (int i = 0; i < 5; ++i) wa.dst[i] = Wt + (size_t)i * DM * DM;
  wconv<<<dim3(16, 16, 5), blk, 0, stream>>>(wa);

  // 2. projections (q dual-output with u/v biases, k, v, p) in one launch
  GArgs ga{};
  ga.A[0] = query; ga.A[1] = key; ga.A[2] = value; ga.A[3] = pos;
  for (int i = 0; i < 4; ++i) ga.Bt[i] = Wt + (size_t)i * DM * DM;
  ga.ba[0] = bq; ga.ba[1] = bk; ga.ba[2] = bv; ga.ba[3] = nullptr;
  ga.bu[0] = u_bias; ga.bv[0] = v_bias;
  ga.oa[0] = qu; ga.oa[1] = kp; ga.oa[2] = vp; ga.oa[3] = pp;
  ga.ob[0] = qv;
  gemm_k<float, false><<<dim3(8, 32, 4), blk, 0, stream>>>(ga, DM);

  // 3. V -> per-head transposed [bh][d][s]
  vtrans<<<dim3(32, 16, 2), blk, 0, stream>>>(vp, vT);

  dim3 g_sc(16, 16, 32);
  if (fast) {
    score_pos<half_t><<<g_sc, blk, 0, stream>>>(qv, pp, scH);
    score_content<half_t><<<g_sc, blk, 0, stream>>>(qu, kp, scH, part);
    av_attn<half_t><<<dim3(16, 32), blk, 0, stream>>>(scH, vT, part, attn, ctx);
  } else {
    float* scF = attn;  // f32 scores in-place in the attn output region
    score_pos<float><<<g_sc, blk, 0, stream>>>(qv, pp, scF);
    score_content<float><<<g_sc, blk, 0, stream>>>(qu, kp, scF, part);
    av_attn<float><<<dim3(16, 32), blk, 0, stream>>>(scF, vT, part, attn, ctx);
  }

  // 4. out = ctx @ Wout^T(t) + bout  (f32 output)
  GArgs go{};
  go.A[0] = ctx; go.Bt[0] = Wt + (size_t)4 * DM * DM;
  go.ba[0] = bout; go.of[0] = out;
  gemm_k<half_t, true><<<dim3(8, 32, 1), blk, 0, stream>>>(go, DM);
}

// Round 3
// 675.447 us; speedup vs baseline: 2.5383x; 1.0229x over previous
//
#include <hip/hip_runtime.h>

#define S_LEN 2048
#define DM    1024
#define NH    16
#define DH    64
#define BATCH 2
#define S2    ((size_t)S_LEN * S_LEN)

typedef _Float16 half_t;
typedef _Float16 f16x8 __attribute__((ext_vector_type(8)));
typedef float    f32x4 __attribute__((ext_vector_type(4)));

// =====================================================================
// global->LDS direct (16B/lane). LDS dest is wave-uniform base + lane*16
// (linear); the XOR tile-swizzle is applied to the per-lane GLOBAL addr
// (both-sides-or-neither rule), reads apply the same XOR.
// =====================================================================
__device__ __forceinline__ void gll16(const void* g, void* l) {
  __builtin_amdgcn_global_load_lds(
      (const __attribute__((address_space(1))) void*)g,
      (__attribute__((address_space(3))) void*)l, 16, 0, 0);
}

// Stage 128 rows x 64 f16 tile. LDS f16 index = r*64 + c'*8;
// content LDS[r][c'] = G[r][c'^(r&7)]  (XOR involution on 8 chunks).
__device__ __forceinline__ void stage_gll(half_t* lds, const half_t* src, int stride) {
  const int t = threadIdx.x, w = t >> 6, lane = t & 63;
  const int c1 = lane & 7, r8 = lane >> 3;
#pragma unroll
  for (int it = 0; it < 4; ++it) {
    int r = w * 32 + it * 8 + r8;                      // r&7 == r8
    const half_t* g = src + (size_t)r * stride + ((c1 ^ r8) << 3);
    gll16(g, lds + (size_t)w * 2048 + it * 512);
  }
}

// per-wave 32 rows x 128 cols over K=64 (2 mfma k-steps), swizzled reads
__device__ __forceinline__ void mfma_block(const half_t* At, const half_t* Bt,
                                           int w, int lane, f32x4 acc[2][8]) {
  const int grp = lane >> 4, li = lane & 15;
#pragma unroll
  for (int ks = 0; ks < 2; ++ks) {
    const int chunk = ks * 4 + grp;
    f16x8 a[2], b[8];
#pragma unroll
    for (int fr = 0; fr < 2; ++fr) {
      int r = w * 32 + fr * 16 + li;
      a[fr] = *(const f16x8*)&At[(size_t)(r * 8 + (chunk ^ (r & 7))) * 8];
    }
#pragma unroll
    for (int fc = 0; fc < 8; ++fc) {
      int r = fc * 16 + li;
      b[fc] = *(const f16x8*)&Bt[(size_t)(r * 8 + (chunk ^ (r & 7))) * 8];
    }
#pragma unroll
    for (int fr = 0; fr < 2; ++fr)
#pragma unroll
      for (int fc = 0; fc < 8; ++fc)
        acc[fr][fc] = __builtin_amdgcn_mfma_f32_16x16x32_f16(a[fr], b[fc], acc[fr][fc], 0, 0, 0);
  }
}

template<typename ST>
__device__ __forceinline__ void load8s(const ST* p, float* o) {
  if constexpr (sizeof(ST) == 2) {
    f16x8 v = *(const f16x8*)p;
#pragma unroll
    for (int e = 0; e < 8; ++e) o[e] = (float)v[e];
  } else {
    const float4* q = (const float4*)p;
    float4 a = q[0], b = q[1];
    o[0]=a.x; o[1]=a.y; o[2]=a.z; o[3]=a.w; o[4]=b.x; o[5]=b.y; o[6]=b.z; o[7]=b.w;
  }
}

// =====================================================================
// Inputs f32 -> f16, one-shot (4 activation matrices)
// =====================================================================
struct AArgs { const float* src[4]; half_t* dst[4]; };

__global__ __launch_bounds__(256) void a2h(AArgs a) {
  const float* s = a.src[blockIdx.y];
  half_t* d = a.dst[blockIdx.y];
  size_t i = ((size_t)blockIdx.x * 256 + threadIdx.x) * 8;
  float4 v0 = *(const float4*)(s + i), v1 = *(const float4*)(s + i + 4);
  f16x8 h;
  h[0]=(half_t)v0.x; h[1]=(half_t)v0.y; h[2]=(half_t)v0.z; h[3]=(half_t)v0.w;
  h[4]=(half_t)v1.x; h[5]=(half_t)v1.y; h[6]=(half_t)v1.z; h[7]=(half_t)v1.w;
  *(f16x8*)(d + i) = h;
}

// =====================================================================
// Weight convert + transpose: W[k][n] f32 -> Wt[n][k] f16  (5 matrices)
// =====================================================================
struct WArgs { const float* src[5]; half_t* dst[5]; };

__global__ __launch_bounds__(256) void wconv(WArgs wa) {
  __shared__ float T[64][65];
  const float* W = wa.src[blockIdx.z];
  half_t* D = wa.dst[blockIdx.z];
  const int k0 = blockIdx.x * 64, n0 = blockIdx.y * 64;
  const int t = threadIdx.x;
#pragma unroll
  for (int it = 0; it < 4; ++it) {
    int idx = t + it * 256; int r = idx >> 4, c4 = (idx & 15) * 4;
    float4 v = *(const float4*)(W + (size_t)(k0 + r) * DM + n0 + c4);
    T[r][c4] = v.x; T[r][c4 + 1] = v.y; T[r][c4 + 2] = v.z; T[r][c4 + 3] = v.w;
  }
  __syncthreads();
#pragma unroll
  for (int it = 0; it < 2; ++it) {
    int idx = t + it * 256; int n = idx >> 3, kc = (idx & 7) * 8;
    f16x8 o;
#pragma unroll
    for (int e = 0; e < 8; ++e) o[e] = (half_t)T[kc + e][n];
    *(f16x8*)&D[(size_t)(n0 + n) * DM + k0 + kc] = o;
  }
}

// =====================================================================
// GEMM: C[M,1024] = A[M,1024](f16) @ Wt[n][k]^T ; z-indexed operand sets.
// =====================================================================
struct GArgs {
  const half_t* A[4];  const half_t* Bt[4];
  const float* ba[4]; const float* bu[4]; const float* bv[4];
  half_t* oa[4]; half_t* ob[4]; float* of[4];
};

template<bool F32OUT>
__global__ __launch_bounds__(256) void gemm_k(GArgs g, int K) {
  __shared__ __align__(16) half_t At[128 * 64];
  __shared__ __align__(16) half_t Bt[128 * 64];
  const int z = blockIdx.z;
  const half_t* A = g.A[z];
  const half_t* B = g.Bt[z];
  const int n0 = blockIdx.x * 128, m0 = blockIdx.y * 128;
  const int t = threadIdx.x, w = t >> 6, lane = t & 63;
  const f32x4 zf = {0.f, 0.f, 0.f, 0.f};
  f32x4 acc[2][8];
#pragma unroll
  for (int i = 0; i < 2; ++i)
#pragma unroll
    for (int j = 0; j < 8; ++j) acc[i][j] = zf;

  for (int k0 = 0; k0 < K; k0 += 64) {
    stage_gll(At, A + (size_t)m0 * K + k0, K);
    stage_gll(Bt, B + (size_t)n0 * K + k0, K);
    __syncthreads();
    mfma_block(At, Bt, w, lane, acc);
    __syncthreads();
  }
  const int grp = lane >> 4, li = lane & 15;
#pragma unroll
  for (int fr = 0; fr < 2; ++fr)
#pragma unroll
    for (int fc = 0; fc < 8; ++fc)
#pragma unroll
      for (int r = 0; r < 4; ++r) {
        int row = m0 + w * 32 + fr * 16 + grp * 4 + r;
        int col = n0 + fc * 16 + li;
        float v = acc[fr][fc][r];
        if (g.ba[z]) v += g.ba[z][col];
        if constexpr (F32OUT) {
          g.of[z][(size_t)row * DM + col] = v;
        } else {
          float v1 = v + (g.bu[z] ? g.bu[z][col] : 0.f);
          g.oa[z][(size_t)row * DM + col] = (half_t)v1;
          if (g.ob[z]) g.ob[z][(size_t)row * DM + col] = (half_t)(v + g.bv[z][col]);
        }
      }
}

// =====================================================================
// V transpose per head: vp[b*S+s][h*64+d] -> vT[bh][d][s]  (f16)
// =====================================================================
__global__ __launch_bounds__(256) void vtrans(const half_t* vp, half_t* vT) {
  __shared__ half_t T[64][72];
  const int s0 = blockIdx.x * 64, h = blockIdx.y, b = blockIdx.z;
  const int t = threadIdx.x;
#pragma unroll
  for (int it = 0; it < 2; ++it) {
    int idx = t + it * 256; int s = idx >> 3, c = idx & 7;
    uint4 v = *(const uint4*)(vp + ((size_t)(b * S_LEN + s0 + s)) * DM + h * DH + c * 8);
    *(uint4*)&T[s][c * 8] = v;
  }
  __syncthreads();
  half_t* dst = vT + ((size_t)(b * NH + h)) * DH * S_LEN;
#pragma unroll
  for (int it = 0; it < 2; ++it) {
    int idx = t + it * 256; int d = idx >> 3, sc = (idx & 7) * 8;
    f16x8 o;
#pragma unroll
    for (int e = 0; e < 8; ++e) o[e] = T[sc + e][d];
    *(f16x8*)&dst[(size_t)d * S_LEN + s0 + sc] = o;
  }
}

// =====================================================================
// Pass 1: pos scores PS[i,j]=(q+v_bias)_i · p_j, scattered via rel-shift
// bijection (incl. zero diagonal) -> sc (raw, unscaled).
// =====================================================================
template<typename ST>
__global__ __launch_bounds__(256) void score_pos(const half_t* qv_, const half_t* pp_, ST* sc) {
  __shared__ __align__(16) half_t At[128 * 64];
  __shared__ __align__(16) half_t Bt[128 * 64];
  const int bh = blockIdx.z, b = bh >> 4, h = bh & 15;
  const int j0 = blockIdx.x * 128, i0 = blockIdx.y * 128;
  const int t = threadIdx.x, w = t >> 6, lane = t & 63;
  stage_gll(At, qv_ + ((size_t)(b * S_LEN + i0)) * DM + h * DH, DM);
  stage_gll(Bt, pp_ + ((size_t)(b * S_LEN + j0)) * DM + h * DH, DM);
  __syncthreads();
  const f32x4 zf = {0.f, 0.f, 0.f, 0.f};
  f32x4 acc[2][8];
#pragma unroll
  for (int i = 0; i < 2; ++i)
#pragma unroll
    for (int j = 0; j < 8; ++j) acc[i][j] = zf;
  mfma_block(At, Bt, w, lane, acc);

  ST* sb = sc + (size_t)bh * S2;
  const int grp = lane >> 4, li = lane & 15;
#pragma unroll
  for (int fr = 0; fr < 2; ++fr)
#pragma unroll
    for (int fc = 0; fc < 8; ++fc)
#pragma unroll
      for (int r = 0; r < 4; ++r) {
        int gi = i0 + w * 32 + fr * 16 + grp * 4 + r;
        int gj = j0 + fc * 16 + li;
        float val = acc[fr][fc][r];
        int tr, tc; float wv;
        if (gi == 0) {
          if (gj == S_LEN - 1) { tr = 0; tc = 0; wv = val; }
          else                 { tr = gj; tc = gj + 1; wv = 0.f; }
        } else if (gj >= S_LEN - 1 - gi) {
          tr = gi;     tc = gi + gj - (S_LEN - 1); wv = val;
        } else {
          tr = gi - 1; tc = gi + gj + 1;           wv = val;
        }
        sb[(size_t)tr * S_LEN + tc] = (ST)wv;
      }
}

// =====================================================================
// Pass 2: content scores (q+u_bias)_i · k_j, RMW-add onto sc, apply /32,
// and emit per-(row, 128-col-tile) softmax partials (max, sumexp).
// =====================================================================
template<typename ST>
__global__ __launch_bounds__(256) void score_content(const half_t* qu_, const half_t* kp_,
                                                     ST* sc, float2* part) {
  __shared__ __align__(16) half_t At[128 * 64];
  __shared__ __align__(16) half_t Bt[128 * 64];
  const int bh = blockIdx.z, b = bh >> 4, h = bh & 15;
  const int k0 = blockIdx.x * 128, i0 = blockIdx.y * 128;
  const int kt = blockIdx.x;
  const int t = threadIdx.x, w = t >> 6, lane = t & 63;
  stage_gll(At, qu_ + ((size_t)(b * S_LEN + i0)) * DM + h * DH, DM);
  stage_gll(Bt, kp_ + ((size_t)(b * S_LEN + k0)) * DM + h * DH, DM);
  __syncthreads();
  const f32x4 zf = {0.f, 0.f, 0.f, 0.f};
  f32x4 acc[2][8];
#pragma unroll
  for (int i = 0; i < 2; ++i)
#pragma unroll
    for (int j = 0; j < 8; ++j) acc[i][j] = zf;
  mfma_block(At, Bt, w, lane, acc);

  ST* sb = sc + (size_t)bh * S2;
  const int grp = lane >> 4, li = lane & 15;
#pragma unroll
  for (int fr = 0; fr < 2; ++fr)
#pragma unroll
    for (int r = 0; r < 4; ++r) {
      int row = i0 + w * 32 + fr * 16 + grp * 4 + r;
      float s[8];
#pragma unroll
      for (int fc = 0; fc < 8; ++fc) {
        int col = k0 + fc * 16 + li;
        size_t off = (size_t)row * S_LEN + col;
        float v = (acc[fr][fc][r] + (float)sb[off]) * 0.03125f;
        sb[off] = (ST)v;
        s[fc] = v;
      }
      float m = s[0];
#pragma unroll
      for (int fc = 1; fc < 8; ++fc) m = fmaxf(m, s[fc]);
#pragma unroll
      for (int d = 1; d < 16; d <<= 1) m = fmaxf(m, __shfl_xor(m, d));
      float l = 0.f;
#pragma unroll
      for (int fc = 0; fc < 8; ++fc) l += __expf(s[fc] - m);
#pragma unroll
      for (int d = 1; d < 16; d <<= 1) l += __shfl_xor(l, d);
      if (li == 0) part[((size_t)bh * S_LEN + row) * 16 + kt] = make_float2(m, l);
    }
}

// =====================================================================
// Pass 3: combine partials -> (M, 1/L); stream score tiles, write final
// f32 attn ONCE, and MFMA p@V -> ctx (f16).  In-place safe for ST=float.
// =====================================================================
template<typename ST>
__global__ __launch_bounds__(256) void av_attn(const ST* sc, const half_t* vT, const float2* part,
                                               float* attn, half_t* ctx) {
  __shared__ __align__(16) half_t Vt[64 * 128];
  __shared__ float Ms[128], Ls[128];
  const int bh = blockIdx.y, b = bh >> 4, h = bh & 15;
  const int q0 = blockIdx.x * 128;
  const int t = threadIdx.x;
  if (t < 128) {
    const float2* pp = part + ((size_t)bh * S_LEN + q0 + t) * 16;
    float M = -3.0e38f;
#pragma unroll
    for (int k = 0; k < 16; ++k) M = fmaxf(M, pp[k].x);
    float L = 0.f;
#pragma unroll
    for (int k = 0; k < 16; ++k) { float2 v = pp[k]; L += v.y * __expf(v.x - M); }
    Ms[t] = M; Ls[t] = 1.f / L;
  }
  const ST* sb = sc + (size_t)bh * S2;
  float* ab = attn + (size_t)bh * S2;
  const half_t* vb = vT + (size_t)bh * (DH * S_LEN);
  const int w = t >> 6, lane = t & 63, grp = lane >> 4, li = lane & 15;
  const int c1 = lane & 15, d4 = lane >> 4;
  const f32x4 zf = {0.f, 0.f, 0.f, 0.f};
  f32x4 acc[2][4];
#pragma unroll
  for (int i = 0; i < 2; ++i)
#pragma unroll
    for (int j = 0; j < 4; ++j) acc[i][j] = zf;

  for (int kt = 0; kt < 16; ++kt) {
    __syncthreads();
    // V tile [64 d][128 s] f16: LDS[d][c'] = V[d][c'^(d&15)], linear dest
#pragma unroll
    for (int it = 0; it < 4; ++it) {
      int d = w * 16 + it * 4 + d4;
      const half_t* g = vb + (size_t)d * S_LEN + kt * 128 + ((c1 ^ (d & 15)) << 3);
      gll16(g, Vt + (size_t)w * 2048 + it * 512);
    }
    __syncthreads();
#pragma unroll
    for (int ks = 0; ks < 4; ++ks) {
      f16x8 pa[2];
#pragma unroll
      for (int fr = 0; fr < 2; ++fr) {
        int r128 = w * 32 + fr * 16 + li;
        int row = q0 + r128;
        int col = kt * 128 + ks * 32 + grp * 8;
        float sv[8];
        load8s(&sb[(size_t)row * S_LEN + col], sv);
        float M = Ms[r128], rL = Ls[r128];
#pragma unroll
        for (int e = 0; e < 8; ++e) sv[e] = __expf(sv[e] - M) * rL;
        float4* dst = (float4*)&ab[(size_t)row * S_LEN + col];
        float4 w0 = {sv[0], sv[1], sv[2], sv[3]};
        float4 w1 = {sv[4], sv[5], sv[6], sv[7]};
        dst[0] = w0; dst[1] = w1;
        f16x8 ph;
#pragma unroll
        for (int e = 0; e < 8; ++e) ph[e] = (half_t)sv[e];
        pa[fr] = ph;
      }
      f16x8 bf[4];
#pragma unroll
      for (int fc = 0; fc < 4; ++fc) {
        int d = fc * 16 + li; int chunk = ks * 4 + grp;
        bf[fc] = *(const f16x8*)&Vt[(size_t)(d * 16 + (chunk ^ (d & 15))) * 8];
      }
#pragma unroll
      for (int fr = 0; fr < 2; ++fr)
#pragma unroll
        for (int fc = 0; fc < 4; ++fc)
          acc[fr][fc] = __builtin_amdgcn_mfma_f32_16x16x32_f16(pa[fr], bf[fc], acc[fr][fc], 0, 0, 0);
    }
  }
#pragma unroll
  for (int fr = 0; fr < 2; ++fr)
#pragma unroll
    for (int fc = 0; fc < 4; ++fc)
#pragma unroll
      for (int r = 0; r < 4; ++r) {
        int q = q0 + w * 32 + fr * 16 + grp * 4 + r;
        int d = fc * 16 + li;
        ctx[((size_t)(b * S_LEN + q)) * DM + h * DH + d] = (half_t)acc[fr][fc][r];
      }
}

// =====================================================================
extern "C" void kernel_launch(void* const* d_in, const int* in_sizes, int n_in,
                              void* d_out, int out_size, void* d_ws, size_t ws_size,
                              hipStream_t stream) {
  (void)in_sizes; (void)n_in; (void)out_size;

  const float* query  = (const float*)d_in[0];
  const float* key    = (const float*)d_in[1];
  const float* value  = (const float*)d_in[2];
  const float* pos    = (const float*)d_in[3];
  const float* Wq     = (const float*)d_in[4];
  const float* bq     = (const float*)d_in[5];
  const float* Wk     = (const float*)d_in[6];
  const float* bk     = (const float*)d_in[7];
  const float* Wv     = (const float*)d_in[8];
  const float* bv     = (const float*)d_in[9];
  const float* Wpos   = (const float*)d_in[10];
  const float* u_bias = (const float*)d_in[11];  // [16,64] == flat [1024]
  const float* v_bias = (const float*)d_in[12];
  const float* Wout   = (const float*)d_in[13];
  const float* bout   = (const float*)d_in[14];

  float* out  = (float*)d_out;
  float* attn = out + (size_t)BATCH * S_LEN * DM;

  char* ws = (char*)d_ws;
  half_t* Wt   = (half_t*)(ws);                 // 5 x 1024x1024 f16 = 10,485,760 B
  half_t* Af16 = (half_t*)(ws + 10485760);      // 4 x 8,388,608 B
  half_t* qu   = (half_t*)(ws + 44040192);
  half_t* qv   = (half_t*)(ws + 52428800);
  half_t* kp   = (half_t*)(ws + 60817408);
  half_t* pp   = (half_t*)(ws + 69206016);
  half_t* vp   = (half_t*)(ws + 77594624);
  half_t* vT   = (half_t*)(ws + 85983232);
  float2* part = (float2*)(ws + 69206016);      // alias pp (dead after pass 1)
  half_t* ctx  = (half_t*)(ws + 77594624);      // alias vp (dead after vtrans)
  half_t* scH  = (half_t*)(ws + 94371840);      // 268,435,456 B if it fits
  const bool fast = ws_size >= (size_t)94371840 + (size_t)BATCH * NH * S2 * 2;

  dim3 blk(256);

  // 0. activations -> f16 (one-shot)
  AArgs aa;
  aa.src[0] = query; aa.src[1] = key; aa.src[2] = value; aa.src[3] = pos;
  for (int i = 0; i < 4; ++i) aa.dst[i] = Af16 + (size_t)i * BATCH * S_LEN * DM;
  a2h<<<dim3(2048, 4), blk, 0, stream>>>(aa);

  // 1. weights -> f16, transposed [n][k]
  WArgs wa;
  wa.src[0] = Wq; wa.src[1] = Wk; wa.src[2] = Wv; wa.src[3] = Wpos; wa.src[4] = Wout;
  for (int i = 0; i < 5; ++i) wa.dst[i] = Wt + (size_t)i * DM * DM;
  wconv<<<dim3(16, 16, 5), blk, 0, stream>>>(wa);

  // 2. projections (q dual-output with u/v biases, k, v, p) in one launch
  GArgs ga{};
  for (int i = 0; i < 4; ++i) {
    ga.A[i]  = Af16 + (size_t)i * BATCH * S_LEN * DM;
    ga.Bt[i] = Wt + (size_t)i * DM * DM;
  }
  ga.ba[0] = bq; ga.ba[1] = bk; ga.ba[2] = bv; ga.ba[3] = nullptr;
  ga.bu[0] = u_bias; ga.bv[0] = v_bias;
  ga.oa[0] = qu; ga.oa[1] = kp; ga.oa[2] = vp; ga.oa[3] = pp;
  ga.ob[0] = qv;
  gemm_k<false><<<dim3(8, 32, 4), blk, 0, stream>>>(ga, DM);

  // 3. V -> per-head transposed [bh][d][s]
  vtrans<<<dim3(32, 16, 2), blk, 0, stream>>>(vp, vT);

  dim3 g_sc(16, 16, 32);
  if (fast) {
    score_pos<half_t><<<g_sc, blk, 0, stream>>>(qv, pp, scH);
    score_content<half_t><<<g_sc, blk, 0, stream>>>(qu, kp, scH, part);
    av_attn<half_t><<<dim3(16, 32), blk, 0, stream>>>(scH, vT, part, attn, ctx);
  } else {
    float* scF = attn;  // f32 scores in-place in the attn output region
    score_pos<float><<<g_sc, blk, 0, stream>>>(qv, pp, scF);
    score_content<float><<<g_sc, blk, 0, stream>>>(qu, kp, scF, part);
    av_attn<float><<<dim3(16, 32), blk, 0, stream>>>(scF, vT, part, attn, ctx);
  }

  // 4. out = ctx @ Wout^T(t) + bout  (f32 output)
  GArgs go{};
  go.A[0] = ctx; go.Bt[0] = Wt + (size_t)4 * DM * DM;
  go.ba[0] = bout; go.of[0] = out;
  gemm_k<true><<<dim3(8, 32, 1), blk, 0, stream>>>(go, DM);
}

// Round 4
// 597.806 us; speedup vs baseline: 2.8680x; 1.1299x over previous
//
#include <hip/hip_runtime.h>

#define S_LEN 2048
#define DM    1024
#define NH    16
#define DH    64
#define BATCH 2
#define S2    ((size_t)S_LEN * S_LEN)

typedef _Float16 half_t;
typedef _Float16 f16x8 __attribute__((ext_vector_type(8)));
typedef _Float16 f16x4 __attribute__((ext_vector_type(4)));
typedef float    f32x4 __attribute__((ext_vector_type(4)));

// =====================================================================
// global->LDS direct (16B/lane). LDS dest wave-linear; XOR swizzle on the
// per-lane GLOBAL address (both-sides-or-neither), reads use the same XOR.
// =====================================================================
__device__ __forceinline__ void gll16(const void* g, void* l) {
  __builtin_amdgcn_global_load_lds(
      (const __attribute__((address_space(1))) void*)g,
      (__attribute__((address_space(3))) void*)l, 16, 0, 0);
}

// 256-thread version (used by gemm_k): 128 rows x 64 f16
__device__ __forceinline__ void stage_gll(half_t* lds, const half_t* src, int stride) {
  const int t = threadIdx.x, w = t >> 6, lane = t & 63;
  const int c1 = lane & 7, r8 = lane >> 3;
#pragma unroll
  for (int it = 0; it < 4; ++it) {
    int r = w * 32 + it * 8 + r8;
    const half_t* g = src + (size_t)r * stride + ((c1 ^ r8) << 3);
    gll16(g, lds + (size_t)w * 2048 + it * 512);
  }
}

// per-wave 32 rows x 128 cols over K=64 (4-wave kernels)
__device__ __forceinline__ void mfma_block(const half_t* At, const half_t* Bt,
                                           int w, int lane, f32x4 acc[2][8]) {
  const int grp = lane >> 4, li = lane & 15;
#pragma unroll
  for (int ks = 0; ks < 2; ++ks) {
    const int chunk = ks * 4 + grp;
    f16x8 a[2], b[8];
#pragma unroll
    for (int fr = 0; fr < 2; ++fr) {
      int r = w * 32 + fr * 16 + li;
      a[fr] = *(const f16x8*)&At[(size_t)(r * 8 + (chunk ^ (r & 7))) * 8];
    }
#pragma unroll
    for (int fc = 0; fc < 8; ++fc) {
      int r = fc * 16 + li;
      b[fc] = *(const f16x8*)&Bt[(size_t)(r * 8 + (chunk ^ (r & 7))) * 8];
    }
#pragma unroll
    for (int fr = 0; fr < 2; ++fr)
#pragma unroll
      for (int fc = 0; fc < 8; ++fc)
        acc[fr][fc] = __builtin_amdgcn_mfma_f32_16x16x32_f16(a[fr], b[fc], acc[fr][fc], 0, 0, 0);
  }
}

template<typename ST>
__device__ __forceinline__ void load8s(const ST* p, float* o) {
  if constexpr (sizeof(ST) == 2) {
    f16x8 v = *(const f16x8*)p;
#pragma unroll
    for (int e = 0; e < 8; ++e) o[e] = (float)v[e];
  } else {
    const float4* q = (const float4*)p;
    float4 a = q[0], b = q[1];
    o[0]=a.x; o[1]=a.y; o[2]=a.z; o[3]=a.w; o[4]=b.x; o[5]=b.y; o[6]=b.z; o[7]=b.w;
  }
}

// =====================================================================
// Inputs f32 -> f16, one-shot; block(0,0) also zeroes the 128B zero-row.
// =====================================================================
struct AArgs { const float* src[4]; half_t* dst[4]; };

__global__ __launch_bounds__(256) void a2h(AArgs a, half_t* zbuf) {
  if (blockIdx.x == 0 && blockIdx.y == 0 && threadIdx.x < 8) {
    float4 z = {0.f, 0.f, 0.f, 0.f};
    ((float4*)zbuf)[threadIdx.x] = z;
  }
  const float* s = a.src[blockIdx.y];
  half_t* d = a.dst[blockIdx.y];
  size_t i = ((size_t)blockIdx.x * 256 + threadIdx.x) * 8;
  float4 v0 = *(const float4*)(s + i), v1 = *(const float4*)(s + i + 4);
  f16x8 h;
  h[0]=(half_t)v0.x; h[1]=(half_t)v0.y; h[2]=(half_t)v0.z; h[3]=(half_t)v0.w;
  h[4]=(half_t)v1.x; h[5]=(half_t)v1.y; h[6]=(half_t)v1.z; h[7]=(half_t)v1.w;
  *(f16x8*)(d + i) = h;
}

// =====================================================================
// Weight convert + transpose: W[k][n] f32 -> Wt[n][k] f16  (5 matrices)
// =====================================================================
struct WArgs { const float* src[5]; half_t* dst[5]; };

__global__ __launch_bounds__(256) void wconv(WArgs wa) {
  __shared__ float T[64][65];
  const float* W = wa.src[blockIdx.z];
  half_t* D = wa.dst[blockIdx.z];
  const int k0 = blockIdx.x * 64, n0 = blockIdx.y * 64;
  const int t = threadIdx.x;
#pragma unroll
  for (int it = 0; it < 4; ++it) {
    int idx = t + it * 256; int r = idx >> 4, c4 = (idx & 15) * 4;
    float4 v = *(const float4*)(W + (size_t)(k0 + r) * DM + n0 + c4);
    T[r][c4] = v.x; T[r][c4 + 1] = v.y; T[r][c4 + 2] = v.z; T[r][c4 + 3] = v.w;
  }
  __syncthreads();
#pragma unroll
  for (int it = 0; it < 2; ++it) {
    int idx = t + it * 256; int n = idx >> 3, kc = (idx & 7) * 8;
    f16x8 o;
#pragma unroll
    for (int e = 0; e < 8; ++e) o[e] = (half_t)T[kc + e][n];
    *(f16x8*)&D[(size_t)(n0 + n) * DM + k0 + kc] = o;
  }
}

// =====================================================================
// GEMM: C[M,1024] = A[M,1024](f16) @ Wt[n][k]^T ; z-indexed operand sets.
// =====================================================================
struct GArgs {
  const half_t* A[4];  const half_t* Bt[4];
  const float* ba[4]; const float* bu[4]; const float* bv[4];
  half_t* oa[4]; half_t* ob[4]; float* of[4];
};

template<bool F32OUT>
__global__ __launch_bounds__(256) void gemm_k(GArgs g, int K) {
  __shared__ __align__(16) half_t At[128 * 64];
  __shared__ __align__(16) half_t Bt[128 * 64];
  const int z = blockIdx.z;
  const half_t* A = g.A[z];
  const half_t* B = g.Bt[z];
  const int n0 = blockIdx.x * 128, m0 = blockIdx.y * 128;
  const int t = threadIdx.x, w = t >> 6, lane = t & 63;
  const f32x4 zf = {0.f, 0.f, 0.f, 0.f};
  f32x4 acc[2][8];
#pragma unroll
  for (int i = 0; i < 2; ++i)
#pragma unroll
    for (int j = 0; j < 8; ++j) acc[i][j] = zf;

  for (int k0 = 0; k0 < K; k0 += 64) {
    stage_gll(At, A + (size_t)m0 * K + k0, K);
    stage_gll(Bt, B + (size_t)n0 * K + k0, K);
    __syncthreads();
    mfma_block(At, Bt, w, lane, acc);
    __syncthreads();
  }
  const int grp = lane >> 4, li = lane & 15;
#pragma unroll
  for (int fr = 0; fr < 2; ++fr)
#pragma unroll
    for (int fc = 0; fc < 8; ++fc)
#pragma unroll
      for (int r = 0; r < 4; ++r) {
        int row = m0 + w * 32 + fr * 16 + grp * 4 + r;
        int col = n0 + fc * 16 + li;
        float v = acc[fr][fc][r];
        if (g.ba[z]) v += g.ba[z][col];
        if constexpr (F32OUT) {
          g.of[z][(size_t)row * DM + col] = v;
        } else {
          float v1 = v + (g.bu[z] ? g.bu[z][col] : 0.f);
          g.oa[z][(size_t)row * DM + col] = (half_t)v1;
          if (g.ob[z]) g.ob[z][(size_t)row * DM + col] = (half_t)(v + g.bv[z][col]);
        }
      }
}

// =====================================================================
// V transpose per head: vp[b*S+s][h*64+d] -> vT[bh][d][s]  (f16)
// =====================================================================
__global__ __launch_bounds__(256) void vtrans(const half_t* vp, half_t* vT) {
  __shared__ half_t T[64][72];
  const int s0 = blockIdx.x * 64, h = blockIdx.y, b = blockIdx.z;
  const int t = threadIdx.x;
#pragma unroll
  for (int it = 0; it < 2; ++it) {
    int idx = t + it * 256; int s = idx >> 3, c = idx & 7;
    uint4 v = *(const uint4*)(vp + ((size_t)(b * S_LEN + s0 + s)) * DM + h * DH + c * 8);
    *(uint4*)&T[s][c * 8] = v;
  }
  __syncthreads();
  half_t* dst = vT + ((size_t)(b * NH + h)) * DH * S_LEN;
#pragma unroll
  for (int it = 0; it < 2; ++it) {
    int idx = t + it * 256; int d = idx >> 3, sc = (idx & 7) * 8;
    f16x8 o;
#pragma unroll
    for (int e = 0; e < 8; ++e) o[e] = T[sc + e][d];
    *(f16x8*)&dst[(size_t)d * S_LEN + s0 + sc] = o;
  }
}

// =====================================================================
// FUSED scores: s[q,k] = (content + shifted pos)/32, written ONCE (f16)
// + per-(row, k-tile) sumexp partials (max-free: |s| <~ 3).
//
// TXL shift identity (local q,k in [0,128), base = 1920 + k0 - i0):
//   e = k - q + 127; jvirt = base + e; j = jvirt mod (S+1);
//   delta = (jvirt >= S+1); rel[q,k] = qv[i0+q+delta] . p[j]
//   (virtual row j==S is a zero row -> diagonal zero falls out)
// Pos band M = QV[144 rows] x Pband[256 rows] via MFMA, stored to LDS in
// fragment layout (b64 conflict-free), shear-read per element (u16).
// =====================================================================
template<typename ST>
__global__ __launch_bounds__(512) void score_fused(
    const half_t* __restrict__ qu_, const half_t* __restrict__ qv_,
    const half_t* __restrict__ kp_, const half_t* __restrict__ pp_,
    const half_t* __restrict__ zbuf, ST* __restrict__ sc, float* __restrict__ part)
{
  __shared__ __align__(16) half_t Mf[36864];    // 72 KB; [0,16K) doubles as QU/K
  __shared__ __align__(16) half_t QV[144 * 64]; // 18 KB
  __shared__ __align__(16) half_t Pb[256 * 64]; // 32 KB
  half_t* QU = Mf;          // phase-1 alias (freed before Mf writes)
  half_t* Kt = Mf + 8192;

  const int bh = blockIdx.z, b = bh >> 4, h = bh & 15;
  const int kt = blockIdx.x, qt = blockIdx.y;
  const int i0 = qt * 128, k0 = kt * 128;
  const int base = 1920 + k0 - i0;              // S-1-127 + (k0-i0), in [0,3840]
  const int t = threadIdx.x, w = t >> 6, lane = t & 63;
  const int grp = lane >> 4, li = lane & 15;

  // ---- stage QU, K (128x64 each), QV (144x64), P band (256x64) ----
  {
    const half_t* srcA = qu_ + ((size_t)(b * S_LEN + i0)) * DM + h * DH;
    const half_t* srcB = kp_ + ((size_t)(b * S_LEN + k0)) * DM + h * DH;
#pragma unroll
    for (int p = 0; p < 2; ++p) {
      int cidx = t + p * 512; int r = cidx >> 3, c = cidx & 7;
      gll16(srcA + (size_t)r * DM + ((c ^ (r & 7)) << 3), QU + (size_t)cidx * 8);
      gll16(srcB + (size_t)r * DM + ((c ^ (r & 7)) << 3), Kt + (size_t)cidx * 8);
    }
  }
#pragma unroll
  for (int p = 0; p < 3; ++p) {                 // QV rows i0..i0+143 (clamped)
    int cidx = t + p * 512;
    if (cidx < 1152) {
      int r = cidx >> 3, c = cidx & 7;
      int grow = i0 + r; if (grow > S_LEN - 1) grow = S_LEN - 1;
      gll16(qv_ + ((size_t)(b * S_LEN + grow)) * DM + h * DH + ((c ^ (r & 7)) << 3),
            QV + (size_t)cidx * 8);
    }
  }
#pragma unroll
  for (int p = 0; p < 4; ++p) {                 // P band, modular gather + zero row
    int cidx = t + p * 512; int e = cidx >> 3, c = cidx & 7;
    int jv = base + e; if (jv >= S_LEN + 1) jv -= (S_LEN + 1);
    const half_t* src = (jv == S_LEN)
        ? (zbuf + ((c ^ (e & 7)) << 3))
        : (pp_ + ((size_t)(b * S_LEN + jv)) * DM + h * DH + ((c ^ (e & 7)) << 3));
    gll16(src, Pb + (size_t)cidx * 8);
  }
  __syncthreads();

  // ---- content MFMA: wave w owns q rows [w*16, w*16+16) ----
  const f32x4 zf = {0.f, 0.f, 0.f, 0.f};
  f32x4 acc_c[8];
#pragma unroll
  for (int j = 0; j < 8; ++j) acc_c[j] = zf;
#pragma unroll
  for (int kk = 0; kk < 2; ++kk) {
    const int chunk = kk * 4 + grp;
    int ra = w * 16 + li;
    f16x8 a = *(const f16x8*)&QU[(size_t)(ra * 8 + (chunk ^ (ra & 7))) * 8];
#pragma unroll
    for (int fc = 0; fc < 8; ++fc) {
      int rb = fc * 16 + li;
      f16x8 bf = *(const f16x8*)&Kt[(size_t)(rb * 8 + (chunk ^ (rb & 7))) * 8];
      acc_c[fc] = __builtin_amdgcn_mfma_f32_16x16x32_f16(a, bf, acc_c[fc], 0, 0, 0);
    }
  }
  __syncthreads();   // QU/K reads complete; Mf region now writable

  // ---- pos band MFMA -> Mf (fragment layout) ----
  // wave w owns e-col-frags {w, w+8}; loop row-frags rf=0..8
  f16x8 bm[2][2];
#pragma unroll
  for (int kk = 0; kk < 2; ++kk)
#pragma unroll
    for (int eci = 0; eci < 2; ++eci) {
      int rb = (w + eci * 8) * 16 + li;
      bm[kk][eci] = *(const f16x8*)&Pb[(size_t)(rb * 8 + ((kk * 4 + grp) ^ (rb & 7))) * 8];
    }
  for (int rf = 0; rf < 9; ++rf) {
    f32x4 am[2] = {zf, zf};
#pragma unroll
    for (int kk = 0; kk < 2; ++kk) {
      int ra = rf * 16 + li;
      f16x8 a = *(const f16x8*)&QV[(size_t)(ra * 8 + ((kk * 4 + grp) ^ (ra & 7))) * 8];
#pragma unroll
      for (int eci = 0; eci < 2; ++eci)
        am[eci] = __builtin_amdgcn_mfma_f32_16x16x32_f16(a, bm[kk][eci], am[eci], 0, 0, 0);
    }
#pragma unroll
    for (int eci = 0; eci < 2; ++eci) {
      int ec = w + eci * 8;
      f16x4 hv;
#pragma unroll
      for (int r = 0; r < 4; ++r) hv[r] = (half_t)am[eci][r];
      *(f16x4*)&Mf[(size_t)(((ec * 9 + rf) * 4 + grp) * 64 + li * 4)] = hv;
    }
  }
  __syncthreads();

  // ---- shear-combine, write s once (coalesced), row sumexp partials ----
  ST* sb = sc + (size_t)bh * S2;
  float lsum[4] = {0.f, 0.f, 0.f, 0.f};
#pragma unroll
  for (int fc = 0; fc < 8; ++fc) {
#pragma unroll
    for (int rr = 0; rr < 4; ++rr) {
      int q = w * 16 + grp * 4 + rr;
      int k = fc * 16 + li;
      int e = k - q + 127;                       // [0,254]
      int jv = base + e;
      int dlt = (jv >= S_LEN + 1) ? 1 : 0;
      int rM = q + dlt;                          // [0,128]
      int ec = e >> 4, ei = e & 15, rf = rM >> 4, ri = rM & 15;
      float mval = (float)Mf[(size_t)(((ec * 9 + rf) * 4 + (ri >> 2)) * 64 + ei * 4 + (ri & 3))];
      float s = (acc_c[fc][rr] + mval) * 0.03125f;
      sb[(size_t)(i0 + q) * S_LEN + k0 + k] = (ST)s;
      lsum[rr] += __expf(s);
    }
  }
#pragma unroll
  for (int rr = 0; rr < 4; ++rr) {
    float v = lsum[rr];
#pragma unroll
    for (int d = 1; d < 16; d <<= 1) v += __shfl_xor(v, d);
    if (li == 0)
      part[((size_t)bh * S_LEN + i0 + w * 16 + grp * 4 + rr) * 16 + kt] = v;
  }
}

// =====================================================================
// Pass 3: combine sumexp partials -> 1/L; stream score tiles, write final
// f32 attn ONCE, and MFMA p@V -> ctx (f16). In-place safe for ST=float.
// =====================================================================
template<typename ST>
__global__ __launch_bounds__(256) void av_attn(const ST* sc, const half_t* vT, const float* part,
                                               float* attn, half_t* ctx) {
  __shared__ __align__(16) half_t Vt[64 * 128];
  __shared__ float Ls[128];
  const int bh = blockIdx.y, b = bh >> 4, h = bh & 15;
  const int q0 = blockIdx.x * 128;
  const int t = threadIdx.x;
  if (t < 128) {
    const float* pp = part + ((size_t)bh * S_LEN + q0 + t) * 16;
    float L = 0.f;
#pragma unroll
    for (int k = 0; k < 16; ++k) L += pp[k];
    Ls[t] = 1.f / L;
  }
  const ST* sb = sc + (size_t)bh * S2;
  float* ab = attn + (size_t)bh * S2;
  const half_t* vb = vT + (size_t)bh * (DH * S_LEN);
  const int w = t >> 6, lane = t & 63, grp = lane >> 4, li = lane & 15;
  const int c1 = lane & 15, d4 = lane >> 4;
  const f32x4 zf = {0.f, 0.f, 0.f, 0.f};
  f32x4 acc[2][4];
#pragma unroll
  for (int i = 0; i < 2; ++i)
#pragma unroll
    for (int j = 0; j < 4; ++j) acc[i][j] = zf;

  for (int kt = 0; kt < 16; ++kt) {
    __syncthreads();
#pragma unroll
    for (int it = 0; it < 4; ++it) {
      int d = w * 16 + it * 4 + d4;
      const half_t* g = vb + (size_t)d * S_LEN + kt * 128 + ((c1 ^ (d & 15)) << 3);
      gll16(g, Vt + (size_t)w * 2048 + it * 512);
    }
    __syncthreads();
#pragma unroll
    for (int ks = 0; ks < 4; ++ks) {
      f16x8 pa[2];
#pragma unroll
      for (int fr = 0; fr < 2; ++fr) {
        int r128 = w * 32 + fr * 16 + li;
        int row = q0 + r128;
        int col = kt * 128 + ks * 32 + grp * 8;
        float sv[8];
        load8s(&sb[(size_t)row * S_LEN + col], sv);
        float rL = Ls[r128];
#pragma unroll
        for (int e = 0; e < 8; ++e) sv[e] = __expf(sv[e]) * rL;
        float4* dst = (float4*)&ab[(size_t)row * S_LEN + col];
        float4 w0 = {sv[0], sv[1], sv[2], sv[3]};
        float4 w1 = {sv[4], sv[5], sv[6], sv[7]};
        dst[0] = w0; dst[1] = w1;
        f16x8 ph;
#pragma unroll
        for (int e = 0; e < 8; ++e) ph[e] = (half_t)sv[e];
        pa[fr] = ph;
      }
      f16x8 bf[4];
#pragma unroll
      for (int fc = 0; fc < 4; ++fc) {
        int d = fc * 16 + li; int chunk = ks * 4 + grp;
        bf[fc] = *(const f16x8*)&Vt[(size_t)(d * 16 + (chunk ^ (d & 15))) * 8];
      }
#pragma unroll
      for (int fr = 0; fr < 2; ++fr)
#pragma unroll
        for (int fc = 0; fc < 4; ++fc)
          acc[fr][fc] = __builtin_amdgcn_mfma_f32_16x16x32_f16(pa[fr], bf[fc], acc[fr][fc], 0, 0, 0);
    }
  }
#pragma unroll
  for (int fr = 0; fr < 2; ++fr)
#pragma unroll
    for (int fc = 0; fc < 4; ++fc)
#pragma unroll
      for (int r = 0; r < 4; ++r) {
        int q = q0 + w * 32 + fr * 16 + grp * 4 + r;
        int d = fc * 16 + li;
        ctx[((size_t)(b * S_LEN + q)) * DM + h * DH + d] = (half_t)acc[fr][fc][r];
      }
}

// =====================================================================
extern "C" void kernel_launch(void* const* d_in, const int* in_sizes, int n_in,
                              void* d_out, int out_size, void* d_ws, size_t ws_size,
                              hipStream_t stream) {
  (void)in_sizes; (void)n_in; (void)out_size;

  const float* query  = (const float*)d_in[0];
  const float* key    = (const float*)d_in[1];
  const float* value  = (const float*)d_in[2];
  const float* pos    = (const float*)d_in[3];
  const float* Wq     = (const float*)d_in[4];
  const float* bq     = (const float*)d_in[5];
  const float* Wk     = (const float*)d_in[6];
  const float* bk     = (const float*)d_in[7];
  const float* Wv     = (const float*)d_in[8];
  const float* bv     = (const float*)d_in[9];
  const float* Wpos   = (const float*)d_in[10];
  const float* u_bias = (const float*)d_in[11];  // [16,64] == flat [1024]
  const float* v_bias = (const float*)d_in[12];
  const float* Wout   = (const float*)d_in[13];
  const float* bout   = (const float*)d_in[14];

  float* out  = (float*)d_out;
  float* attn = out + (size_t)BATCH * S_LEN * DM;

  char* ws = (char*)d_ws;
  half_t* Wt   = (half_t*)(ws);                 // 5 x 1024x1024 f16 = 10,485,760 B
  half_t* Af16 = (half_t*)(ws + 10485760);      // 4 x 8,388,608 B (dead after proj)
  float*  part = (float*)(ws + 10485760);       // 4 MB, aliases Af16 post-proj
  half_t* qu   = (half_t*)(ws + 44040192);
  half_t* qv   = (half_t*)(ws + 52428800);
  half_t* kp   = (half_t*)(ws + 60817408);
  half_t* pp   = (half_t*)(ws + 69206016);
  half_t* vp   = (half_t*)(ws + 77594624);
  half_t* vT   = (half_t*)(ws + 85983232);
  half_t* ctx  = (half_t*)(ws + 77594624);      // alias vp (dead after vtrans)
  half_t* zbuf = (half_t*)(ws + 94371840);      // 128 B zero row
  half_t* scH  = (half_t*)(ws + 94375936);      // 268,435,456 B if it fits
  const bool fast = ws_size >= (size_t)94375936 + (size_t)BATCH * NH * S2 * 2;

  dim3 blk(256);

  // 0. activations -> f16 (one-shot) + zero-row init
  AArgs aa;
  aa.src[0] = query; aa.src[1] = key; aa.src[2] = value; aa.src[3] = pos;
  for (int i = 0; i < 4; ++i) aa.dst[i] = Af16 + (size_t)i * BATCH * S_LEN * DM;
  a2h<<<dim3(2048, 4), blk, 0, stream>>>(aa, zbuf);

  // 1. weights -> f16, transposed [n][k]
  WArgs wa;
  wa.src[0] = Wq; wa.src[1] = Wk; wa.src[2] = Wv; wa.src[3] = Wpos; wa.src[4] = Wout;
  for (int i = 0; i < 5; ++i) wa.dst[i] = Wt + (size_t)i * DM * DM;
  wconv<<<dim3(16, 16, 5), blk, 0, stream>>>(wa);

  // 2. projections (q dual-output with u/v biases, k, v, p) in one launch
  GArgs ga{};
  for (int i = 0; i < 4; ++i) {
    ga.A[i]  = Af16 + (size_t)i * BATCH * S_LEN * DM;
    ga.Bt[i] = Wt + (size_t)i * DM * DM;
  }
  ga.ba[0] = bq; ga.ba[1] = bk; ga.ba[2] = bv; ga.ba[3] = nullptr;
  ga.bu[0] = u_bias; ga.bv[0] = v_bias;
  ga.oa[0] = qu; ga.oa[1] = kp; ga.oa[2] = vp; ga.oa[3] = pp;
  ga.ob[0] = qv;
  gemm_k<false><<<dim3(8, 32, 4), blk, 0, stream>>>(ga, DM);

  // 3. V -> per-head transposed [bh][d][s]
  vtrans<<<dim3(32, 16, 2), blk, 0, stream>>>(vp, vT);

  // 4. fused scores (content + band pos + shear), 5. attn + PV
  dim3 g_sc(16, 16, 32);
  dim3 blk5(512);
  if (fast) {
    score_fused<half_t><<<g_sc, blk5, 0, stream>>>(qu, qv, kp, pp, zbuf, scH, part);
    av_attn<half_t><<<dim3(16, 32), blk, 0, stream>>>(scH, vT, part, attn, ctx);
  } else {
    float* scF = attn;  // f32 scores in-place in the attn output region
    score_fused<float><<<g_sc, blk5, 0, stream>>>(qu, qv, kp, pp, zbuf, scF, part);
    av_attn<float><<<dim3(16, 32), blk, 0, stream>>>(scF, vT, part, attn, ctx);
  }

  // 6. out = ctx @ Wout^T + bout  (f32 output)
  GArgs go{};
  go.A[0] = ctx; go.Bt[0] = Wt + (size_t)4 * DM * DM;
  go.ba[0] = bout; go.of[0] = out;
  gemm_k<true><<<dim3(8, 32, 1), blk, 0, stream>>>(go, DM);
}

// Round 5
// 585.791 us; speedup vs baseline: 2.9268x; 1.0205x over previous
//
#include <hip/hip_runtime.h>

#define S_LEN 2048
#define DM    1024
#define NH    16
#define DH    64
#define BATCH 2
#define S2    ((size_t)S_LEN * S_LEN)

typedef _Float16 half_t;
typedef _Float16 f16x8 __attribute__((ext_vector_type(8)));
typedef _Float16 f16x4 __attribute__((ext_vector_type(4)));
typedef float    f32x4 __attribute__((ext_vector_type(4)));

// =====================================================================
// global->LDS direct (16B/lane). LDS dest wave-linear; XOR swizzle on the
// per-lane GLOBAL address (both-sides-or-neither), reads use the same XOR.
// =====================================================================
__device__ __forceinline__ void gll16(const void* g, void* l) {
  __builtin_amdgcn_global_load_lds(
      (const __attribute__((address_space(1))) void*)g,
      (__attribute__((address_space(3))) void*)l, 16, 0, 0);
}

// 256-thread version (used by gemm_k): 128 rows x 64 f16
__device__ __forceinline__ void stage_gll(half_t* lds, const half_t* src, int stride) {
  const int t = threadIdx.x, w = t >> 6, lane = t & 63;
  const int c1 = lane & 7, r8 = lane >> 3;
#pragma unroll
  for (int it = 0; it < 4; ++it) {
    int r = w * 32 + it * 8 + r8;
    const half_t* g = src + (size_t)r * stride + ((c1 ^ r8) << 3);
    gll16(g, lds + (size_t)w * 2048 + it * 512);
  }
}

// per-wave 32 rows x 128 cols over K=64 (4-wave kernels)
__device__ __forceinline__ void mfma_block(const half_t* At, const half_t* Bt,
                                           int w, int lane, f32x4 acc[2][8]) {
  const int grp = lane >> 4, li = lane & 15;
#pragma unroll
  for (int ks = 0; ks < 2; ++ks) {
    const int chunk = ks * 4 + grp;
    f16x8 a[2], b[8];
#pragma unroll
    for (int fr = 0; fr < 2; ++fr) {
      int r = w * 32 + fr * 16 + li;
      a[fr] = *(const f16x8*)&At[(size_t)(r * 8 + (chunk ^ (r & 7))) * 8];
    }
#pragma unroll
    for (int fc = 0; fc < 8; ++fc) {
      int r = fc * 16 + li;
      b[fc] = *(const f16x8*)&Bt[(size_t)(r * 8 + (chunk ^ (r & 7))) * 8];
    }
#pragma unroll
    for (int fr = 0; fr < 2; ++fr)
#pragma unroll
      for (int fc = 0; fc < 8; ++fc)
        acc[fr][fc] = __builtin_amdgcn_mfma_f32_16x16x32_f16(a[fr], b[fc], acc[fr][fc], 0, 0, 0);
  }
}

template<typename ST>
__device__ __forceinline__ void load8s(const ST* p, float* o) {
  if constexpr (sizeof(ST) == 2) {
    f16x8 v = *(const f16x8*)p;
#pragma unroll
    for (int e = 0; e < 8; ++e) o[e] = (float)v[e];
  } else {
    const float4* q = (const float4*)p;
    float4 a = q[0], b = q[1];
    o[0]=a.x; o[1]=a.y; o[2]=a.z; o[3]=a.w; o[4]=b.x; o[5]=b.y; o[6]=b.z; o[7]=b.w;
  }
}

// =====================================================================
// Inputs f32 -> f16, one-shot; block(0,0) also zeroes the 128B zero-row.
// =====================================================================
struct AArgs { const float* src[4]; half_t* dst[4]; };

__global__ __launch_bounds__(256) void a2h(AArgs a, half_t* zbuf) {
  if (blockIdx.x == 0 && blockIdx.y == 0 && threadIdx.x < 8) {
    float4 z = {0.f, 0.f, 0.f, 0.f};
    ((float4*)zbuf)[threadIdx.x] = z;
  }
  const float* s = a.src[blockIdx.y];
  half_t* d = a.dst[blockIdx.y];
  size_t i = ((size_t)blockIdx.x * 256 + threadIdx.x) * 8;
  float4 v0 = *(const float4*)(s + i), v1 = *(const float4*)(s + i + 4);
  f16x8 h;
  h[0]=(half_t)v0.x; h[1]=(half_t)v0.y; h[2]=(half_t)v0.z; h[3]=(half_t)v0.w;
  h[4]=(half_t)v1.x; h[5]=(half_t)v1.y; h[6]=(half_t)v1.z; h[7]=(half_t)v1.w;
  *(f16x8*)(d + i) = h;
}

// =====================================================================
// Weight convert + transpose: W[k][n] f32 -> Wt[n][k] f16  (5 matrices)
// =====================================================================
struct WArgs { const float* src[5]; half_t* dst[5]; };

__global__ __launch_bounds__(256) void wconv(WArgs wa) {
  __shared__ float T[64][65];
  const float* W = wa.src[blockIdx.z];
  half_t* D = wa.dst[blockIdx.z];
  const int k0 = blockIdx.x * 64, n0 = blockIdx.y * 64;
  const int t = threadIdx.x;
#pragma unroll
  for (int it = 0; it < 4; ++it) {
    int idx = t + it * 256; int r = idx >> 4, c4 = (idx & 15) * 4;
    float4 v = *(const float4*)(W + (size_t)(k0 + r) * DM + n0 + c4);
    T[r][c4] = v.x; T[r][c4 + 1] = v.y; T[r][c4 + 2] = v.z; T[r][c4 + 3] = v.w;
  }
  __syncthreads();
#pragma unroll
  for (int it = 0; it < 2; ++it) {
    int idx = t + it * 256; int n = idx >> 3, kc = (idx & 7) * 8;
    f16x8 o;
#pragma unroll
    for (int e = 0; e < 8; ++e) o[e] = (half_t)T[kc + e][n];
    *(f16x8*)&D[(size_t)(n0 + n) * DM + k0 + kc] = o;
  }
}

// =====================================================================
// GEMM: C[M,1024] = A[M,1024](f16) @ Wt[n][k]^T ; z-indexed operand sets.
// 2-phase double-buffered staging (stage k+1 overlaps MFMA of k).
// =====================================================================
struct GArgs {
  const half_t* A[4];  const half_t* Bt[4];
  const float* ba[4]; const float* bu[4]; const float* bv[4];
  half_t* oa[4]; half_t* ob[4]; float* of[4];
};

template<bool F32OUT>
__global__ __launch_bounds__(256) void gemm_k(GArgs g, int K) {
  __shared__ __align__(16) half_t At[2][128 * 64];
  __shared__ __align__(16) half_t Bt[2][128 * 64];
  const int z = blockIdx.z;
  const half_t* A = g.A[z];
  const half_t* B = g.Bt[z];
  const int n0 = blockIdx.x * 128, m0 = blockIdx.y * 128;
  const int t = threadIdx.x, w = t >> 6, lane = t & 63;
  const f32x4 zf = {0.f, 0.f, 0.f, 0.f};
  f32x4 acc[2][8];
#pragma unroll
  for (int i = 0; i < 2; ++i)
#pragma unroll
    for (int j = 0; j < 8; ++j) acc[i][j] = zf;

  stage_gll(At[0], A + (size_t)m0 * K, K);
  stage_gll(Bt[0], B + (size_t)n0 * K, K);
  __syncthreads();
  int cur = 0;
  for (int k0 = 0; k0 < K; k0 += 64) {
    int nk = k0 + 64;
    if (nk < K) {
      stage_gll(At[cur ^ 1], A + (size_t)m0 * K + nk, K);
      stage_gll(Bt[cur ^ 1], B + (size_t)n0 * K + nk, K);
    }
    mfma_block(At[cur], Bt[cur], w, lane, acc);
    __syncthreads();   // drains vmcnt (stage of k+1) + lgkm; one barrier/iter
    cur ^= 1;
  }
  const int grp = lane >> 4, li = lane & 15;
#pragma unroll
  for (int fr = 0; fr < 2; ++fr)
#pragma unroll
    for (int fc = 0; fc < 8; ++fc)
#pragma unroll
      for (int r = 0; r < 4; ++r) {
        int row = m0 + w * 32 + fr * 16 + grp * 4 + r;
        int col = n0 + fc * 16 + li;
        float v = acc[fr][fc][r];
        if (g.ba[z]) v += g.ba[z][col];
        if constexpr (F32OUT) {
          g.of[z][(size_t)row * DM + col] = v;
        } else {
          float v1 = v + (g.bu[z] ? g.bu[z][col] : 0.f);
          g.oa[z][(size_t)row * DM + col] = (half_t)v1;
          if (g.ob[z]) g.ob[z][(size_t)row * DM + col] = (half_t)(v + g.bv[z][col]);
        }
      }
}

// =====================================================================
// V transpose per head: vp[b*S+s][h*64+d] -> vT[bh][d][s]  (f16)
// =====================================================================
__global__ __launch_bounds__(256) void vtrans(const half_t* vp, half_t* vT) {
  __shared__ half_t T[64][72];
  const int s0 = blockIdx.x * 64, h = blockIdx.y, b = blockIdx.z;
  const int t = threadIdx.x;
#pragma unroll
  for (int it = 0; it < 2; ++it) {
    int idx = t + it * 256; int s = idx >> 3, c = idx & 7;
    uint4 v = *(const uint4*)(vp + ((size_t)(b * S_LEN + s0 + s)) * DM + h * DH + c * 8);
    *(uint4*)&T[s][c * 8] = v;
  }
  __syncthreads();
  half_t* dst = vT + ((size_t)(b * NH + h)) * DH * S_LEN;
#pragma unroll
  for (int it = 0; it < 2; ++it) {
    int idx = t + it * 256; int d = idx >> 3, sc = (idx & 7) * 8;
    f16x8 o;
#pragma unroll
    for (int e = 0; e < 8; ++e) o[e] = T[sc + e][d];
    *(f16x8*)&dst[(size_t)d * S_LEN + s0 + sc] = o;
  }
}

// =====================================================================
// FUSED scores: writes EXP(s) once (f16), s = (content + shifted pos)/32,
// + per-(row, k-tile) sumexp partials (max-free: |s| <~ 3).
//
// TXL shift identity (local q,k in [0,128), base = 1920 + k0 - i0):
//   e = k - q + 127; jvirt = base + e; j = jvirt mod (S+1);
//   delta = (jvirt >= S+1); rel[q,k] = qv[i0+q+delta] . p[j]
//   (virtual row j==S is a zero row -> diagonal zero falls out)
// =====================================================================
template<typename ST>
__global__ __launch_bounds__(512) void score_fused(
    const half_t* __restrict__ qu_, const half_t* __restrict__ qv_,
    const half_t* __restrict__ kp_, const half_t* __restrict__ pp_,
    const half_t* __restrict__ zbuf, ST* __restrict__ sc, float* __restrict__ part)
{
  __shared__ __align__(16) half_t Mf[36864];    // 72 KB; [0,16K) doubles as QU/K
  __shared__ __align__(16) half_t QV[144 * 64]; // 18 KB
  __shared__ __align__(16) half_t Pb[256 * 64]; // 32 KB
  half_t* QU = Mf;          // phase-1 alias (freed before Mf writes)
  half_t* Kt = Mf + 8192;

  const int bh = blockIdx.z, b = bh >> 4, h = bh & 15;
  const int kt = blockIdx.x, qt = blockIdx.y;
  const int i0 = qt * 128, k0 = kt * 128;
  const int base = 1920 + k0 - i0;              // S-1-127 + (k0-i0), in [0,3840]
  const int t = threadIdx.x, w = t >> 6, lane = t & 63;
  const int grp = lane >> 4, li = lane & 15;

  // ---- stage QU, K (128x64 each), QV (144x64), P band (256x64) ----
  {
    const half_t* srcA = qu_ + ((size_t)(b * S_LEN + i0)) * DM + h * DH;
    const half_t* srcB = kp_ + ((size_t)(b * S_LEN + k0)) * DM + h * DH;
#pragma unroll
    for (int p = 0; p < 2; ++p) {
      int cidx = t + p * 512; int r = cidx >> 3, c = cidx & 7;
      gll16(srcA + (size_t)r * DM + ((c ^ (r & 7)) << 3), QU + (size_t)cidx * 8);
      gll16(srcB + (size_t)r * DM + ((c ^ (r & 7)) << 3), Kt + (size_t)cidx * 8);
    }
  }
#pragma unroll
  for (int p = 0; p < 3; ++p) {                 // QV rows i0..i0+143 (clamped)
    int cidx = t + p * 512;
    if (cidx < 1152) {
      int r = cidx >> 3, c = cidx & 7;
      int grow = i0 + r; if (grow > S_LEN - 1) grow = S_LEN - 1;
      gll16(qv_ + ((size_t)(b * S_LEN + grow)) * DM + h * DH + ((c ^ (r & 7)) << 3),
            QV + (size_t)cidx * 8);
    }
  }
#pragma unroll
  for (int p = 0; p < 4; ++p) {                 // P band, modular gather + zero row
    int cidx = t + p * 512; int e = cidx >> 3, c = cidx & 7;
    int jv = base + e; if (jv >= S_LEN + 1) jv -= (S_LEN + 1);
    const half_t* src = (jv == S_LEN)
        ? (zbuf + ((c ^ (e & 7)) << 3))
        : (pp_ + ((size_t)(b * S_LEN + jv)) * DM + h * DH + ((c ^ (e & 7)) << 3));
    gll16(src, Pb + (size_t)cidx * 8);
  }
  __syncthreads();

  // ---- content MFMA: wave w owns q rows [w*16, w*16+16) ----
  const f32x4 zf = {0.f, 0.f, 0.f, 0.f};
  f32x4 acc_c[8];
#pragma unroll
  for (int j = 0; j < 8; ++j) acc_c[j] = zf;
#pragma unroll
  for (int kk = 0; kk < 2; ++kk) {
    const int chunk = kk * 4 + grp;
    int ra = w * 16 + li;
    f16x8 a = *(const f16x8*)&QU[(size_t)(ra * 8 + (chunk ^ (ra & 7))) * 8];
#pragma unroll
    for (int fc = 0; fc < 8; ++fc) {
      int rb = fc * 16 + li;
      f16x8 bf = *(const f16x8*)&Kt[(size_t)(rb * 8 + (chunk ^ (rb & 7))) * 8];
      acc_c[fc] = __builtin_amdgcn_mfma_f32_16x16x32_f16(a, bf, acc_c[fc], 0, 0, 0);
    }
  }
  __syncthreads();   // QU/K reads complete; Mf region now writable

  // ---- pos band MFMA -> Mf (fragment layout) ----
  // wave w owns e-col-frags {w, w+8}; loop row-frags rf=0..8
  f16x8 bm[2][2];
#pragma unroll
  for (int kk = 0; kk < 2; ++kk)
#pragma unroll
    for (int eci = 0; eci < 2; ++eci) {
      int rb = (w + eci * 8) * 16 + li;
      bm[kk][eci] = *(const f16x8*)&Pb[(size_t)(rb * 8 + ((kk * 4 + grp) ^ (rb & 7))) * 8];
    }
  for (int rf = 0; rf < 9; ++rf) {
    f32x4 am[2] = {zf, zf};
#pragma unroll
    for (int kk = 0; kk < 2; ++kk) {
      int ra = rf * 16 + li;
      f16x8 a = *(const f16x8*)&QV[(size_t)(ra * 8 + ((kk * 4 + grp) ^ (ra & 7))) * 8];
#pragma unroll
      for (int eci = 0; eci < 2; ++eci)
        am[eci] = __builtin_amdgcn_mfma_f32_16x16x32_f16(a, bm[kk][eci], am[eci], 0, 0, 0);
    }
#pragma unroll
    for (int eci = 0; eci < 2; ++eci) {
      int ec = w + eci * 8;
      f16x4 hv;
#pragma unroll
      for (int r = 0; r < 4; ++r) hv[r] = (half_t)am[eci][r];
      *(f16x4*)&Mf[(size_t)(((ec * 9 + rf) * 4 + grp) * 64 + li * 4)] = hv;
    }
  }
  __syncthreads();

  // ---- shear-combine, write exp(s) once (coalesced), row sumexp partials ----
  ST* sb = sc + (size_t)bh * S2;
  float lsum[4] = {0.f, 0.f, 0.f, 0.f};
#pragma unroll
  for (int fc = 0; fc < 8; ++fc) {
#pragma unroll
    for (int rr = 0; rr < 4; ++rr) {
      int q = w * 16 + grp * 4 + rr;
      int k = fc * 16 + li;
      int e = k - q + 127;                       // [0,254]
      int jv = base + e;
      int dlt = (jv >= S_LEN + 1) ? 1 : 0;
      int rM = q + dlt;                          // [0,128]
      int ec = e >> 4, ei = e & 15, rf = rM >> 4, ri = rM & 15;
      float mval = (float)Mf[(size_t)(((ec * 9 + rf) * 4 + (ri >> 2)) * 64 + ei * 4 + (ri & 3))];
      float s = (acc_c[fc][rr] + mval) * 0.03125f;
      float ev = __expf(s);
      sb[(size_t)(i0 + q) * S_LEN + k0 + k] = (ST)ev;
      lsum[rr] += ev;
    }
  }
#pragma unroll
  for (int rr = 0; rr < 4; ++rr) {
    float v = lsum[rr];
#pragma unroll
    for (int d = 1; d < 16; d <<= 1) v += __shfl_xor(v, d);
    if (li == 0)
      part[((size_t)bh * S_LEN + i0 + w * 16 + grp * 4 + rr) * 16 + kt] = v;
  }
}

// =====================================================================
// Pass 3: combine sumexp partials -> 1/L; stream exp tiles, scale by 1/L,
// write final f32 attn ONCE, and MFMA p@V -> ctx (f16).
// V staging double-buffered (2-phase). In-place safe for ST=float.
// =====================================================================
template<typename ST>
__global__ __launch_bounds__(256) void av_attn(const ST* sc, const half_t* vT, const float* part,
                                               float* attn, half_t* ctx) {
  __shared__ __align__(16) half_t Vt[2][64 * 128];
  __shared__ float Ls[128];
  const int bh = blockIdx.y, b = bh >> 4, h = bh & 15;
  const int q0 = blockIdx.x * 128;
  const int t = threadIdx.x;
  if (t < 128) {
    const float* pp = part + ((size_t)bh * S_LEN + q0 + t) * 16;
    float L = 0.f;
#pragma unroll
    for (int k = 0; k < 16; ++k) L += pp[k];
    Ls[t] = 1.f / L;
  }
  const ST* sb = sc + (size_t)bh * S2;
  float* ab = attn + (size_t)bh * S2;
  const half_t* vb = vT + (size_t)bh * (DH * S_LEN);
  const int w = t >> 6, lane = t & 63, grp = lane >> 4, li = lane & 15;
  const int c1 = lane & 15, d4 = lane >> 4;
  const f32x4 zf = {0.f, 0.f, 0.f, 0.f};
  f32x4 acc[2][4];
#pragma unroll
  for (int i = 0; i < 2; ++i)
#pragma unroll
    for (int j = 0; j < 4; ++j) acc[i][j] = zf;

  // prologue stage kt=0
#pragma unroll
  for (int it = 0; it < 4; ++it) {
    int d = w * 16 + it * 4 + d4;
    gll16(vb + (size_t)d * S_LEN + ((c1 ^ (d & 15)) << 3), Vt[0] + (size_t)w * 2048 + it * 512);
  }
  __syncthreads();
  int cur = 0;

  for (int kt = 0; kt < 16; ++kt) {
    if (kt + 1 < 16) {
#pragma unroll
      for (int it = 0; it < 4; ++it) {
        int d = w * 16 + it * 4 + d4;
        gll16(vb + (size_t)d * S_LEN + (kt + 1) * 128 + ((c1 ^ (d & 15)) << 3),
              Vt[cur ^ 1] + (size_t)w * 2048 + it * 512);
      }
    }
#pragma unroll
    for (int ks = 0; ks < 4; ++ks) {
      f16x8 pa[2];
#pragma unroll
      for (int fr = 0; fr < 2; ++fr) {
        int r128 = w * 32 + fr * 16 + li;
        int row = q0 + r128;
        int col = kt * 128 + ks * 32 + grp * 8;
        float sv[8];
        load8s(&sb[(size_t)row * S_LEN + col], sv);
        float rL = Ls[r128];
#pragma unroll
        for (int e = 0; e < 8; ++e) sv[e] *= rL;
        float4* dst = (float4*)&ab[(size_t)row * S_LEN + col];
        float4 w0 = {sv[0], sv[1], sv[2], sv[3]};
        float4 w1 = {sv[4], sv[5], sv[6], sv[7]};
        dst[0] = w0; dst[1] = w1;
        f16x8 ph;
#pragma unroll
        for (int e = 0; e < 8; ++e) ph[e] = (half_t)sv[e];
        pa[fr] = ph;
      }
      f16x8 bf[4];
#pragma unroll
      for (int fc = 0; fc < 4; ++fc) {
        int d = fc * 16 + li; int chunk = ks * 4 + grp;
        bf[fc] = *(const f16x8*)&Vt[cur][(size_t)(d * 16 + (chunk ^ (d & 15))) * 8];
      }
#pragma unroll
      for (int fr = 0; fr < 2; ++fr)
#pragma unroll
        for (int fc = 0; fc < 4; ++fc)
          acc[fr][fc] = __builtin_amdgcn_mfma_f32_16x16x32_f16(pa[fr], bf[fc], acc[fr][fc], 0, 0, 0);
    }
    __syncthreads();   // drains stage of kt+1; one barrier/iter
    cur ^= 1;
  }
#pragma unroll
  for (int fr = 0; fr < 2; ++fr)
#pragma unroll
    for (int fc = 0; fc < 4; ++fc)
#pragma unroll
      for (int r = 0; r < 4; ++r) {
        int q = q0 + w * 32 + fr * 16 + grp * 4 + r;
        int d = fc * 16 + li;
        ctx[((size_t)(b * S_LEN + q)) * DM + h * DH + d] = (half_t)acc[fr][fc][r];
      }
}

// =====================================================================
extern "C" void kernel_launch(void* const* d_in, const int* in_sizes, int n_in,
                              void* d_out, int out_size, void* d_ws, size_t ws_size,
                              hipStream_t stream) {
  (void)in_sizes; (void)n_in; (void)out_size;

  const float* query  = (const float*)d_in[0];
  const float* key    = (const float*)d_in[1];
  const float* value  = (const float*)d_in[2];
  const float* pos    = (const float*)d_in[3];
  const float* Wq     = (const float*)d_in[4];
  const float* bq     = (const float*)d_in[5];
  const float* Wk     = (const float*)d_in[6];
  const float* bk     = (const float*)d_in[7];
  const float* Wv     = (const float*)d_in[8];
  const float* bv     = (const float*)d_in[9];
  const float* Wpos   = (const float*)d_in[10];
  const float* u_bias = (const float*)d_in[11];  // [16,64] == flat [1024]
  const float* v_bias = (const float*)d_in[12];
  const float* bout   = (const float*)d_in[14];
  const float* Wout   = (const float*)d_in[13];

  float* out  = (float*)d_out;
  float* attn = out + (size_t)BATCH * S_LEN * DM;

  char* ws = (char*)d_ws;
  half_t* Wt   = (half_t*)(ws);                 // 5 x 1024x1024 f16 = 10,485,760 B
  half_t* Af16 = (half_t*)(ws + 10485760);      // 4 x 8,388,608 B (dead after proj)
  float*  part = (float*)(ws + 10485760);       // 4 MB, aliases Af16 post-proj
  half_t* qu   = (half_t*)(ws + 44040192);
  half_t* qv   = (half_t*)(ws + 52428800);
  half_t* kp   = (half_t*)(ws + 60817408);
  half_t* pp   = (half_t*)(ws + 69206016);
  half_t* vp   = (half_t*)(ws + 77594624);
  half_t* vT   = (half_t*)(ws + 85983232);
  half_t* ctx  = (half_t*)(ws + 77594624);      // alias vp (dead after vtrans)
  half_t* zbuf = (half_t*)(ws + 94371840);      // 128 B zero row
  half_t* scH  = (half_t*)(ws + 94375936);      // 268,435,456 B if it fits
  const bool fast = ws_size >= (size_t)94375936 + (size_t)BATCH * NH * S2 * 2;

  dim3 blk(256);

  // 0. activations -> f16 (one-shot) + zero-row init
  AArgs aa;
  aa.src[0] = query; aa.src[1] = key; aa.src[2] = value; aa.src[3] = pos;
  for (int i = 0; i < 4; ++i) aa.dst[i] = Af16 + (size_t)i * BATCH * S_LEN * DM;
  a2h<<<dim3(2048, 4), blk, 0, stream>>>(aa, zbuf);

  // 1. weights -> f16, transposed [n][k]
  WArgs wa;
  wa.src[0] = Wq; wa.src[1] = Wk; wa.src[2] = Wv; wa.src[3] = Wpos; wa.src[4] = Wout;
  for (int i = 0; i < 5; ++i) wa.dst[i] = Wt + (size_t)i * DM * DM;
  wconv<<<dim3(16, 16, 5), blk, 0, stream>>>(wa);

  // 2. projections (q dual-output with u/v biases, k, v, p) in one launch
  GArgs ga{};
  for (int i = 0; i < 4; ++i) {
    ga.A[i]  = Af16 + (size_t)i * BATCH * S_LEN * DM;
    ga.Bt[i] = Wt + (size_t)i * DM * DM;
  }
  ga.ba[0] = bq; ga.ba[1] = bk; ga.ba[2] = bv; ga.ba[3] = nullptr;
  ga.bu[0] = u_bias; ga.bv[0] = v_bias;
  ga.oa[0] = qu; ga.oa[1] = kp; ga.oa[2] = vp; ga.oa[3] = pp;
  ga.ob[0] = qv;
  gemm_k<false><<<dim3(8, 32, 4), blk, 0, stream>>>(ga, DM);

  // 3. V -> per-head transposed [bh][d][s]
  vtrans<<<dim3(32, 16, 2), blk, 0, stream>>>(vp, vT);

  // 4. fused scores (content + band pos + shear, exp stored), 5. attn + PV
  dim3 g_sc(16, 16, 32);
  dim3 blk5(512);
  if (fast) {
    score_fused<half_t><<<g_sc, blk5, 0, stream>>>(qu, qv, kp, pp, zbuf, scH, part);
    av_attn<half_t><<<dim3(16, 32), blk, 0, stream>>>(scH, vT, part, attn, ctx);
  } else {
    float* scF = attn;  // f32 exp-scores in-place in the attn output region
    score_fused<float><<<g_sc, blk5, 0, stream>>>(qu, qv, kp, pp, zbuf, scF, part);
    av_attn<float><<<dim3(16, 32), blk, 0, stream>>>(scF, vT, part, attn, ctx);
  }

  // 6. out = ctx @ Wout^T + bout  (f32 output)
  GArgs go{};
  go.A[0] = ctx; go.Bt[0] = Wt + (size_t)4 * DM * DM;
  go.ba[0] = bout; go.of[0] = out;
  gemm_k<true><<<dim3(8, 32, 1), blk, 0, stream>>>(go, DM);
}

// Round 7
// 542.739 us; speedup vs baseline: 3.1590x; 1.0793x over previous
//
#include <hip/hip_runtime.h>

#define S_LEN 2048
#define DM    1024
#define NH    16
#define DH    64
#define BATCH 2
#define S2    ((size_t)S_LEN * S_LEN)

typedef _Float16 half_t;
typedef _Float16 f16x8 __attribute__((ext_vector_type(8)));
typedef _Float16 f16x4 __attribute__((ext_vector_type(4)));
typedef float    f32x4 __attribute__((ext_vector_type(4)));

// =====================================================================
// global->LDS direct (16B/lane). LDS dest wave-linear; XOR swizzle on the
// per-lane GLOBAL address (both-sides-or-neither), reads use the same XOR.
// =====================================================================
__device__ __forceinline__ void gll16(const void* g, void* l) {
  __builtin_amdgcn_global_load_lds(
      (const __attribute__((address_space(1))) void*)g,
      (__attribute__((address_space(3))) void*)l, 16, 0, 0);
}

// 256-thread version (used by gemm_k): 128 rows x 64 f16
__device__ __forceinline__ void stage_gll(half_t* lds, const half_t* src, int stride) {
  const int t = threadIdx.x, w = t >> 6, lane = t & 63;
  const int c1 = lane & 7, r8 = lane >> 3;
#pragma unroll
  for (int it = 0; it < 4; ++it) {
    int r = w * 32 + it * 8 + r8;
    const half_t* g = src + (size_t)r * stride + ((c1 ^ r8) << 3);
    gll16(g, lds + (size_t)w * 2048 + it * 512);
  }
}

// per-wave 32 rows x 128 cols over K=64 (4-wave kernels)
__device__ __forceinline__ void mfma_block(const half_t* At, const half_t* Bt,
                                           int w, int lane, f32x4 acc[2][8]) {
  const int grp = lane >> 4, li = lane & 15;
#pragma unroll
  for (int ks = 0; ks < 2; ++ks) {
    const int chunk = ks * 4 + grp;
    f16x8 a[2], b[8];
#pragma unroll
    for (int fr = 0; fr < 2; ++fr) {
      int r = w * 32 + fr * 16 + li;
      a[fr] = *(const f16x8*)&At[(size_t)(r * 8 + (chunk ^ (r & 7))) * 8];
    }
#pragma unroll
    for (int fc = 0; fc < 8; ++fc) {
      int r = fc * 16 + li;
      b[fc] = *(const f16x8*)&Bt[(size_t)(r * 8 + (chunk ^ (r & 7))) * 8];
    }
#pragma unroll
    for (int fr = 0; fr < 2; ++fr)
#pragma unroll
      for (int fc = 0; fc < 8; ++fc)
        acc[fr][fc] = __builtin_amdgcn_mfma_f32_16x16x32_f16(a[fr], b[fc], acc[fr][fc], 0, 0, 0);
  }
}

template<typename ST>
__device__ __forceinline__ void load8s(const ST* p, float* o) {
  if constexpr (sizeof(ST) == 2) {
    f16x8 v = *(const f16x8*)p;
#pragma unroll
    for (int e = 0; e < 8; ++e) o[e] = (float)v[e];
  } else {
    const float4* q = (const float4*)p;
    float4 a = q[0], b = q[1];
    o[0]=a.x; o[1]=a.y; o[2]=a.z; o[3]=a.w; o[4]=b.x; o[5]=b.y; o[6]=b.z; o[7]=b.w;
  }
}

// =====================================================================
// Inputs f32 -> f16, one-shot; block(0,0) also zeroes the 128B zero-row.
// =====================================================================
struct AArgs { const float* src[4]; half_t* dst[4]; };

__global__ __launch_bounds__(256) void a2h(AArgs a, half_t* zbuf) {
  if (blockIdx.x == 0 && blockIdx.y == 0 && threadIdx.x < 8) {
    float4 z = {0.f, 0.f, 0.f, 0.f};
    ((float4*)zbuf)[threadIdx.x] = z;
  }
  const float* s = a.src[blockIdx.y];
  half_t* d = a.dst[blockIdx.y];
  size_t i = ((size_t)blockIdx.x * 256 + threadIdx.x) * 8;
  float4 v0 = *(const float4*)(s + i), v1 = *(const float4*)(s + i + 4);
  f16x8 h;
  h[0]=(half_t)v0.x; h[1]=(half_t)v0.y; h[2]=(half_t)v0.z; h[3]=(half_t)v0.w;
  h[4]=(half_t)v1.x; h[5]=(half_t)v1.y; h[6]=(half_t)v1.z; h[7]=(half_t)v1.w;
  *(f16x8*)(d + i) = h;
}

// =====================================================================
// Weight convert + transpose: W[k][n] f32 -> Wt[n][k] f16  (5 matrices)
// =====================================================================
struct WArgs { const float* src[5]; half_t* dst[5]; };

__global__ __launch_bounds__(256) void wconv(WArgs wa) {
  __shared__ float T[64][65];
  const float* W = wa.src[blockIdx.z];
  half_t* D = wa.dst[blockIdx.z];
  const int k0 = blockIdx.x * 64, n0 = blockIdx.y * 64;
  const int t = threadIdx.x;
#pragma unroll
  for (int it = 0; it < 4; ++it) {
    int idx = t + it * 256; int r = idx >> 4, c4 = (idx & 15) * 4;
    float4 v = *(const float4*)(W + (size_t)(k0 + r) * DM + n0 + c4);
    T[r][c4] = v.x; T[r][c4 + 1] = v.y; T[r][c4 + 2] = v.z; T[r][c4 + 3] = v.w;
  }
  __syncthreads();
#pragma unroll
  for (int it = 0; it < 2; ++it) {
    int idx = t + it * 256; int n = idx >> 3, kc = (idx & 7) * 8;
    f16x8 o;
#pragma unroll
    for (int e = 0; e < 8; ++e) o[e] = (half_t)T[kc + e][n];
    *(f16x8*)&D[(size_t)(n0 + n) * DM + k0 + kc] = o;
  }
}

// =====================================================================
// GEMM: C[M,1024] = A[M,1024](f16) @ Wt[n][k]^T ; z-indexed operand sets.
// 2-phase double-buffered staging (stage k+1 overlaps MFMA of k).
// =====================================================================
struct GArgs {
  const half_t* A[4];  const half_t* Bt[4];
  const float* ba[4]; const float* bu[4]; const float* bv[4];
  half_t* oa[4]; half_t* ob[4]; float* of[4];
};

template<bool F32OUT>
__global__ __launch_bounds__(256) void gemm_k(GArgs g, int K) {
  __shared__ __align__(16) half_t At[2][128 * 64];
  __shared__ __align__(16) half_t Bt[2][128 * 64];
  const int z = blockIdx.z;
  const half_t* A = g.A[z];
  const half_t* B = g.Bt[z];
  const int n0 = blockIdx.x * 128, m0 = blockIdx.y * 128;
  const int t = threadIdx.x, w = t >> 6, lane = t & 63;
  const f32x4 zf = {0.f, 0.f, 0.f, 0.f};
  f32x4 acc[2][8];
#pragma unroll
  for (int i = 0; i < 2; ++i)
#pragma unroll
    for (int j = 0; j < 8; ++j) acc[i][j] = zf;

  stage_gll(At[0], A + (size_t)m0 * K, K);
  stage_gll(Bt[0], B + (size_t)n0 * K, K);
  __syncthreads();
  int cur = 0;
  for (int k0 = 0; k0 < K; k0 += 64) {
    int nk = k0 + 64;
    if (nk < K) {
      stage_gll(At[cur ^ 1], A + (size_t)m0 * K + nk, K);
      stage_gll(Bt[cur ^ 1], B + (size_t)n0 * K + nk, K);
    }
    mfma_block(At[cur], Bt[cur], w, lane, acc);
    __syncthreads();   // drains vmcnt (stage of k+1) + lgkm; one barrier/iter
    cur ^= 1;
  }
  const int grp = lane >> 4, li = lane & 15;
#pragma unroll
  for (int fr = 0; fr < 2; ++fr)
#pragma unroll
    for (int fc = 0; fc < 8; ++fc)
#pragma unroll
      for (int r = 0; r < 4; ++r) {
        int row = m0 + w * 32 + fr * 16 + grp * 4 + r;
        int col = n0 + fc * 16 + li;
        float v = acc[fr][fc][r];
        if (g.ba[z]) v += g.ba[z][col];
        if constexpr (F32OUT) {
          g.of[z][(size_t)row * DM + col] = v;
        } else {
          float v1 = v + (g.bu[z] ? g.bu[z][col] : 0.f);
          g.oa[z][(size_t)row * DM + col] = (half_t)v1;
          if (g.ob[z]) g.ob[z][(size_t)row * DM + col] = (half_t)(v + g.bv[z][col]);
        }
      }
}

// =====================================================================
// V transpose per head: vp[b*S+s][h*64+d] -> vT[bh][d][s]  (f16)
// =====================================================================
__global__ __launch_bounds__(256) void vtrans(const half_t* vp, half_t* vT) {
  __shared__ half_t T[64][72];
  const int s0 = blockIdx.x * 64, h = blockIdx.y, b = blockIdx.z;
  const int t = threadIdx.x;
#pragma unroll
  for (int it = 0; it < 2; ++it) {
    int idx = t + it * 256; int s = idx >> 3, c = idx & 7;
    uint4 v = *(const uint4*)(vp + ((size_t)(b * S_LEN + s0 + s)) * DM + h * DH + c * 8);
    *(uint4*)&T[s][c * 8] = v;
  }
  __syncthreads();
  half_t* dst = vT + ((size_t)(b * NH + h)) * DH * S_LEN;
#pragma unroll
  for (int it = 0; it < 2; ++it) {
    int idx = t + it * 256; int d = idx >> 3, sc = (idx & 7) * 8;
    f16x8 o;
#pragma unroll
    for (int e = 0; e < 8; ++e) o[e] = T[sc + e][d];
    *(f16x8*)&dst[(size_t)d * S_LEN + s0 + sc] = o;
  }
}

// =====================================================================
// FUSED scores: writes EXP(s) once (f16), s = (content + shifted pos)/32,
// + per-(row, k-tile) sumexp partials (max-free: |s| <~ 3).
//
// TXL shift identity (local q,k in [0,128), base = 1920 + k0 - i0):
//   e = k - q + 127; jvirt = base + e; j = jvirt mod (S+1);
//   delta = (jvirt >= S+1); rel[q,k] = qv[i0+q+delta] . p[j]
//   (virtual row j==S is a zero row -> diagonal zero falls out)
//
// 80KB LDS exactly -> 2 blocks/CU. Layout:
//   RegA 64KB: phase1 {QU 16K | Kt 16K | Pb 32K}
//              phase2 Mf: 16ec x 8rf x 4grp x 64h fragment layout (FULL width).
//   QV 16KB (rows 0..127).
// Row rM=128 (only consumed at q=127, where e=k<128): A-operand for the
// 9th row-frag comes from qv row i0+128 loaded DIRECT TO REGISTERS; its
// 128 results are embedded in Mf's unconsumed (ec==15, li==15) slots
// (e=255 is never read):  m128_addr(e) = ((120+(e>>4))*4+((e>>2)&3))*64+60+(e&3).
// =====================================================================
template<typename ST>
__global__ __launch_bounds__(512, 4) void score_fused(
    const half_t* __restrict__ qu_, const half_t* __restrict__ qv_,
    const half_t* __restrict__ kp_, const half_t* __restrict__ pp_,
    const half_t* __restrict__ zbuf, ST* __restrict__ sc, float* __restrict__ part)
{
  __shared__ __align__(16) half_t RegA[32768];  // 64 KB
  __shared__ __align__(16) half_t QV[128 * 64]; // 16 KB
  half_t* QU = RegA;            // phase 1
  half_t* Kt = RegA + 8192;
  half_t* Pb = RegA + 16384;
  half_t* Mf = RegA;            // phase 2: full 32768 halfs

  const int bh = blockIdx.z, b = bh >> 4, h = bh & 15;
  const int kt = blockIdx.x, qt = blockIdx.y;
  const int i0 = qt * 128, k0 = kt * 128;
  const int base = 1920 + k0 - i0;              // in [0,3840]
  const int t = threadIdx.x, w = t >> 6, lane = t & 63;
  const int grp = lane >> 4, li = lane & 15;

  // ---- stage QU, Kt, QV (128x64 each), P band (256x64) ----
  {
    const half_t* srcA = qu_ + ((size_t)(b * S_LEN + i0)) * DM + h * DH;
    const half_t* srcB = kp_ + ((size_t)(b * S_LEN + k0)) * DM + h * DH;
    const half_t* srcQ = qv_ + ((size_t)(b * S_LEN + i0)) * DM + h * DH;
#pragma unroll
    for (int p = 0; p < 2; ++p) {
      int cidx = t + p * 512; int r = cidx >> 3, c = cidx & 7;
      size_t off = (size_t)r * DM + ((c ^ (r & 7)) << 3);
      gll16(srcA + off, QU + (size_t)cidx * 8);
      gll16(srcB + off, Kt + (size_t)cidx * 8);
      gll16(srcQ + off, QV + (size_t)cidx * 8);
    }
  }
#pragma unroll
  for (int p = 0; p < 4; ++p) {                 // P band, modular gather + zero row
    int cidx = t + p * 512; int e = cidx >> 3, c = cidx & 7;
    int jv = base + e; if (jv >= S_LEN + 1) jv -= (S_LEN + 1);
    const half_t* src = (jv == S_LEN)
        ? (zbuf + ((c ^ (e & 7)) << 3))
        : (pp_ + ((size_t)(b * S_LEN + jv)) * DM + h * DH + ((c ^ (e & 7)) << 3));
    gll16(src, Pb + (size_t)cidx * 8);
  }

  // qv row i0+128 -> registers (chunk kk*4+grp of the 64-half row; linear,
  // matches the deswizzled A-fragment layout). Clamped row is never consumed.
  f16x8 aq[2];
  {
    int r128 = i0 + 128; if (r128 > S_LEN - 1) r128 = S_LEN - 1;
    const half_t* q128p = qv_ + ((size_t)(b * S_LEN + r128)) * DM + h * DH;
    aq[0] = *(const f16x8*)(q128p + (0 * 4 + grp) * 8);
    aq[1] = *(const f16x8*)(q128p + (1 * 4 + grp) * 8);
  }
  __syncthreads();

  // ---- content MFMA (reads QU,Kt) + bm loads (reads Pb) ----
  const f32x4 zf = {0.f, 0.f, 0.f, 0.f};
  f32x4 acc_c[8];
#pragma unroll
  for (int j = 0; j < 8; ++j) acc_c[j] = zf;
#pragma unroll
  for (int kk = 0; kk < 2; ++kk) {
    const int chunk = kk * 4 + grp;
    int ra = w * 16 + li;
    f16x8 a = *(const f16x8*)&QU[(size_t)(ra * 8 + (chunk ^ (ra & 7))) * 8];
#pragma unroll
    for (int fc = 0; fc < 8; ++fc) {
      int rb = fc * 16 + li;
      f16x8 bf = *(const f16x8*)&Kt[(size_t)(rb * 8 + (chunk ^ (rb & 7))) * 8];
      acc_c[fc] = __builtin_amdgcn_mfma_f32_16x16x32_f16(a, bf, acc_c[fc], 0, 0, 0);
    }
  }
  f16x8 bm[2][2];                               // all of Pb register-cached
#pragma unroll
  for (int kk = 0; kk < 2; ++kk)
#pragma unroll
    for (int eci = 0; eci < 2; ++eci) {
      int rb = (w + eci * 8) * 16 + li;
      bm[kk][eci] = *(const f16x8*)&Pb[(size_t)(rb * 8 + ((kk * 4 + grp) ^ (rb & 7))) * 8];
    }
  __syncthreads();   // all QU/Kt/Pb reads done; RegA now writable as Mf

  // ---- pos band MFMA rf=0..7 -> Mf (full-width fragment layout) ----
  for (int rf = 0; rf < 8; ++rf) {
    f32x4 am[2] = {zf, zf};
#pragma unroll
    for (int kk = 0; kk < 2; ++kk) {
      int ra = rf * 16 + li;
      f16x8 a = *(const f16x8*)&QV[(size_t)(ra * 8 + ((kk * 4 + grp) ^ (ra & 7))) * 8];
#pragma unroll
      for (int eci = 0; eci < 2; ++eci)
        am[eci] = __builtin_amdgcn_mfma_f32_16x16x32_f16(a, bm[kk][eci], am[eci], 0, 0, 0);
    }
#pragma unroll
    for (int eci = 0; eci < 2; ++eci) {
      int ec = w + eci * 8;
      if (!(ec == 15 && li == 15)) {            // keep (ec15,li15) slots free
        f16x4 hv;
#pragma unroll
        for (int r = 0; r < 4; ++r) hv[r] = (half_t)am[eci][r];
        *(f16x4*)&Mf[(size_t)(((ec * 8 + rf) * 4 + grp) * 64 + li * 4)] = hv;
      }
    }
  }

  // ---- 9th row-frag (row i0+128): A broadcast from registers; results for
  //      e = w*16+li (<128) go into the free (ec==15, li==15) slots ----
  {
    f32x4 am0 = zf;
#pragma unroll
    for (int kk = 0; kk < 2; ++kk)
      am0 = __builtin_amdgcn_mfma_f32_16x16x32_f16(aq[kk], bm[kk][0], am0, 0, 0, 0);
    if (grp == 0) {
      int e = w * 16 + li;                      // w<8 always (8 waves)
      Mf[(size_t)(((120 + (e >> 4)) * 4 + ((e >> 2) & 3)) * 64 + 60 + (e & 3))] = (half_t)am0[0];
    }
  }
  __syncthreads();

  // ---- shear-combine, write exp(s) once (coalesced), row sumexp partials ----
  ST* sb = sc + (size_t)bh * S2;
  float lsum[4] = {0.f, 0.f, 0.f, 0.f};
#pragma unroll
  for (int fc = 0; fc < 8; ++fc) {
#pragma unroll
    for (int rr = 0; rr < 4; ++rr) {
      int q = w * 16 + grp * 4 + rr;
      int k = fc * 16 + li;
      int e = k - q + 127;                       // [0,254]
      int jv = base + e;
      int dlt = (jv >= S_LEN + 1) ? 1 : 0;
      int rM = q + dlt;                          // [0,128]
      float mval;
      if (rM < 128) {
        int ec = e >> 4, ei = e & 15, rf = rM >> 4, ri = rM & 15;
        mval = (float)Mf[(size_t)(((ec * 8 + rf) * 4 + (ri >> 2)) * 64 + ei * 4 + (ri & 3))];
      } else {                                   // rM==128 -> q==127, e=k<128
        mval = (float)Mf[(size_t)(((120 + (e >> 4)) * 4 + ((e >> 2) & 3)) * 64 + 60 + (e & 3))];
      }
      float s = (acc_c[fc][rr] + mval) * 0.03125f;
      float ev = __expf(s);
      sb[(size_t)(i0 + q) * S_LEN + k0 + k] = (ST)ev;
      lsum[rr] += ev;
    }
  }
#pragma unroll
  for (int rr = 0; rr < 4; ++rr) {
    float v = lsum[rr];
#pragma unroll
    for (int d = 1; d < 16; d <<= 1) v += __shfl_xor(v, d);
    if (li == 0)
      part[((size_t)bh * S_LEN + i0 + w * 16 + grp * 4 + rr) * 16 + kt] = v;
  }
}

// =====================================================================
// Pass 3: combine sumexp partials -> 1/L; stream exp tiles, scale by 1/L,
// write final f32 attn ONCE, and MFMA p@V -> ctx (f16).
// V staging double-buffered (2-phase). In-place safe for ST=float.
// =====================================================================
template<typename ST>
__global__ __launch_bounds__(256) void av_attn(const ST* sc, const half_t* vT, const float* part,
                                               float* attn, half_t* ctx) {
  __shared__ __align__(16) half_t Vt[2][64 * 128];
  __shared__ float Ls[128];
  const int bh = blockIdx.y, b = bh >> 4, h = bh & 15;
  const int q0 = blockIdx.x * 128;
  const int t = threadIdx.x;
  if (t < 128) {
    const float* pp = part + ((size_t)bh * S_LEN + q0 + t) * 16;
    float L = 0.f;
#pragma unroll
    for (int k = 0; k < 16; ++k) L += pp[k];
    Ls[t] = 1.f / L;
  }
  const ST* sb = sc + (size_t)bh * S2;
  float* ab = attn + (size_t)bh * S2;
  const half_t* vb = vT + (size_t)bh * (DH * S_LEN);
  const int w = t >> 6, lane = t & 63, grp = lane >> 4, li = lane & 15;
  const int c1 = lane & 15, d4 = lane >> 4;
  const f32x4 zf = {0.f, 0.f, 0.f, 0.f};
  f32x4 acc[2][4];
#pragma unroll
  for (int i = 0; i < 2; ++i)
#pragma unroll
    for (int j = 0; j < 4; ++j) acc[i][j] = zf;

  // prologue stage kt=0
#pragma unroll
  for (int it = 0; it < 4; ++it) {
    int d = w * 16 + it * 4 + d4;
    gll16(vb + (size_t)d * S_LEN + ((c1 ^ (d & 15)) << 3), Vt[0] + (size_t)w * 2048 + it * 512);
  }
  __syncthreads();
  int cur = 0;

  for (int kt = 0; kt < 16; ++kt) {
    if (kt + 1 < 16) {
#pragma unroll
      for (int it = 0; it < 4; ++it) {
        int d = w * 16 + it * 4 + d4;
        gll16(vb + (size_t)d * S_LEN + (kt + 1) * 128 + ((c1 ^ (d & 15)) << 3),
              Vt[cur ^ 1] + (size_t)w * 2048 + it * 512);
      }
    }
#pragma unroll
    for (int ks = 0; ks < 4; ++ks) {
      f16x8 pa[2];
#pragma unroll
      for (int fr = 0; fr < 2; ++fr) {
        int r128 = w * 32 + fr * 16 + li;
        int row = q0 + r128;
        int col = kt * 128 + ks * 32 + grp * 8;
        float sv[8];
        load8s(&sb[(size_t)row * S_LEN + col], sv);
        float rL = Ls[r128];
#pragma unroll
        for (int e = 0; e < 8; ++e) sv[e] *= rL;
        float4* dst = (float4*)&ab[(size_t)row * S_LEN + col];
        float4 w0 = {sv[0], sv[1], sv[2], sv[3]};
        float4 w1 = {sv[4], sv[5], sv[6], sv[7]};
        dst[0] = w0; dst[1] = w1;
        f16x8 ph;
#pragma unroll
        for (int e = 0; e < 8; ++e) ph[e] = (half_t)sv[e];
        pa[fr] = ph;
      }
      f16x8 bf[4];
#pragma unroll
      for (int fc = 0; fc < 4; ++fc) {
        int d = fc * 16 + li; int chunk = ks * 4 + grp;
        bf[fc] = *(const f16x8*)&Vt[cur][(size_t)(d * 16 + (chunk ^ (d & 15))) * 8];
      }
#pragma unroll
      for (int fr = 0; fr < 2; ++fr)
#pragma unroll
        for (int fc = 0; fc < 4; ++fc)
          acc[fr][fc] = __builtin_amdgcn_mfma_f32_16x16x32_f16(pa[fr], bf[fc], acc[fr][fc], 0, 0, 0);
    }
    __syncthreads();   // drains stage of kt+1; one barrier/iter
    cur ^= 1;
  }
#pragma unroll
  for (int fr = 0; fr < 2; ++fr)
#pragma unroll
    for (int fc = 0; fc < 4; ++fc)
#pragma unroll
      for (int r = 0; r < 4; ++r) {
        int q = q0 + w * 32 + fr * 16 + grp * 4 + r;
        int d = fc * 16 + li;
        ctx[((size_t)(b * S_LEN + q)) * DM + h * DH + d] = (half_t)acc[fr][fc][r];
      }
}

// =====================================================================
extern "C" void kernel_launch(void* const* d_in, const int* in_sizes, int n_in,
                              void* d_out, int out_size, void* d_ws, size_t ws_size,
                              hipStream_t stream) {
  (void)in_sizes; (void)n_in; (void)out_size;

  const float* query  = (const float*)d_in[0];
  const float* key    = (const float*)d_in[1];
  const float* value  = (const float*)d_in[2];
  const float* pos    = (const float*)d_in[3];
  const float* Wq     = (const float*)d_in[4];
  const float* bq     = (const float*)d_in[5];
  const float* Wk     = (const float*)d_in[6];
  const float* bk     = (const float*)d_in[7];
  const float* Wv     = (const float*)d_in[8];
  const float* bv     = (const float*)d_in[9];
  const float* Wpos   = (const float*)d_in[10];
  const float* u_bias = (const float*)d_in[11];  // [16,64] == flat [1024]
  const float* v_bias = (const float*)d_in[12];
  const float* Wout   = (const float*)d_in[13];
  const float* bout   = (const float*)d_in[14];

  float* out  = (float*)d_out;
  float* attn = out + (size_t)BATCH * S_LEN * DM;

  char* ws = (char*)d_ws;
  half_t* Wt   = (half_t*)(ws);                 // 5 x 1024x1024 f16 = 10,485,760 B
  half_t* Af16 = (half_t*)(ws + 10485760);      // 4 x 8,388,608 B (dead after proj)
  float*  part = (float*)(ws + 10485760);       // 4 MB, aliases Af16 post-proj
  half_t* qu   = (half_t*)(ws + 44040192);
  half_t* qv   = (half_t*)(ws + 52428800);
  half_t* kp   = (half_t*)(ws + 60817408);
  half_t* pp   = (half_t*)(ws + 69206016);
  half_t* vp   = (half_t*)(ws + 77594624);
  half_t* vT   = (half_t*)(ws + 85983232);
  half_t* ctx  = (half_t*)(ws + 77594624);      // alias vp (dead after vtrans)
  half_t* zbuf = (half_t*)(ws + 94371840);      // 128 B zero row
  half_t* scH  = (half_t*)(ws + 94375936);      // 268,435,456 B if it fits
  const bool fast = ws_size >= (size_t)94375936 + (size_t)BATCH * NH * S2 * 2;

  dim3 blk(256);

  // 0. activations -> f16 (one-shot) + zero-row init
  AArgs aa;
  aa.src[0] = query; aa.src[1] = key; aa.src[2] = value; aa.src[3] = pos;
  for (int i = 0; i < 4; ++i) aa.dst[i] = Af16 + (size_t)i * BATCH * S_LEN * DM;
  a2h<<<dim3(2048, 4), blk, 0, stream>>>(aa, zbuf);

  // 1. weights -> f16, transposed [n][k]
  WArgs wa;
  wa.src[0] = Wq; wa.src[1] = Wk; wa.src[2] = Wv; wa.src[3] = Wpos; wa.src[4] = Wout;
  for (int i = 0; i < 5; ++i) wa.dst[i] = Wt + (size_t)i * DM * DM;
  wconv<<<dim3(16, 16, 5), blk, 0, stream>>>(wa);

  // 2. projections (q dual-output with u/v biases, k, v, p) in one launch
  GArgs ga{};
  for (int i = 0; i < 4; ++i) {
    ga.A[i]  = Af16 + (size_t)i * BATCH * S_LEN * DM;
    ga.Bt[i] = Wt + (size_t)i * DM * DM;
  }
  ga.ba[0] = bq; ga.ba[1] = bk; ga.ba[2] = bv; ga.ba[3] = nullptr;
  ga.bu[0] = u_bias; ga.bv[0] = v_bias;
  ga.oa[0] = qu; ga.oa[1] = kp; ga.oa[2] = vp; ga.oa[3] = pp;
  ga.ob[0] = qv;
  gemm_k<false><<<dim3(8, 32, 4), blk, 0, stream>>>(ga, DM);

  // 3. V -> per-head transposed [bh][d][s]
  vtrans<<<dim3(32, 16, 2), blk, 0, stream>>>(vp, vT);

  // 4. fused scores (content + band pos + shear, exp stored), 5. attn + PV
  dim3 g_sc(16, 16, 32);
  dim3 blk5(512);
  if (fast) {
    score_fused<half_t><<<g_sc, blk5, 0, stream>>>(qu, qv, kp, pp, zbuf, scH, part);
    av_attn<half_t><<<dim3(16, 32), blk, 0, stream>>>(scH, vT, part, attn, ctx);
  } else {
    float* scF = attn;  // f32 exp-scores in-place in the attn output region
    score_fused<float><<<g_sc, blk5, 0, stream>>>(qu, qv, kp, pp, zbuf, scF, part);
    av_attn<float><<<dim3(16, 32), blk, 0, stream>>>(scF, vT, part, attn, ctx);
  }

  // 6. out = ctx @ Wout^T + bout  (f32 output)
  GArgs go{};
  go.A[0] = ctx; go.Bt[0] = Wt + (size_t)4 * DM * DM;
  go.ba[0] = bout; go.of[0] = out;
  gemm_k<true><<<dim3(8, 32, 1), blk, 0, stream>>>(go, DM);
}